// Round 9
// baseline (281.337 us; speedup 1.0000x reference)
//
#include <hip/hip_runtime.h>

#define Vv 32000
#define Ll 2048

typedef __bf16 bf16x8 __attribute__((ext_vector_type(8)));
typedef float  f32x4  __attribute__((ext_vector_type(4)));

__device__ __forceinline__ unsigned short f2bf(float f) {
    unsigned u = __builtin_bit_cast(unsigned, f);
    u += 0x7fffu + ((u >> 16) & 1u);
    return (unsigned short)(u >> 16);
}
__device__ __forceinline__ float bf2f(unsigned short s) {
    unsigned u = (unsigned)s << 16;
    return __builtin_bit_cast(float, u);
}
__device__ __forceinline__ void unpk8(uint4 v, float* o) {
    o[0] = bf2f((unsigned short)(v.x & 0xffff)); o[1] = bf2f((unsigned short)(v.x >> 16));
    o[2] = bf2f((unsigned short)(v.y & 0xffff)); o[3] = bf2f((unsigned short)(v.y >> 16));
    o[4] = bf2f((unsigned short)(v.z & 0xffff)); o[5] = bf2f((unsigned short)(v.z >> 16));
    o[6] = bf2f((unsigned short)(v.w & 0xffff)); o[7] = bf2f((unsigned short)(v.w >> 16));
}

#define MFMA(a, b, c) __builtin_amdgcn_mfma_f32_16x16x32_bf16(a, b, c, 0, 0, 0)
#define GLL16(gsrc, ldst)                                                    \
    __builtin_amdgcn_global_load_lds(                                        \
        (const __attribute__((address_space(1))) void*)(gsrc),               \
        (__attribute__((address_space(3))) void*)(ldst), 16, 0, 0)
#define GLL4(gsrc, ldst)                                                     \
    __builtin_amdgcn_global_load_lds(                                        \
        (const __attribute__((address_space(1))) void*)(gsrc),               \
        (__attribute__((address_space(3))) void*)(ldst), 4, 0, 0)

// ---------------- prep: transpose W1/W2/Wp to bf16 [N][K]; zero pad row ----
__global__ __launch_bounds__(256) void prep_kernel(
    const float* __restrict__ W1, const float* __restrict__ W2,
    const float* __restrict__ Wp, unsigned short* __restrict__ W1T,
    unsigned short* __restrict__ W2T, unsigned short* __restrict__ WpT,
    float* __restrict__ zrow)
{
    int idx = blockIdx.x * 256 + threadIdx.x;   // pair index
    if (blockIdx.x == 575 && threadIdx.x < 64) zrow[threadIdx.x] = 0.f;
    if (idx < 65536) {                           // W1T [512][256] <- W1 [256][512]
        int e0 = idx * 2, n = e0 >> 8, k = e0 & 255;
        unsigned lo = f2bf(W1[(size_t)k * 512 + n]);
        unsigned hi = f2bf(W1[(size_t)(k + 1) * 512 + n]);
        ((unsigned*)W1T)[idx] = lo | (hi << 16);
    } else if (idx < 131072) {                   // W2T [256][512] <- W2 [512][256]
        int i = idx - 65536, e0 = i * 2, n = e0 >> 9, k = e0 & 511;
        unsigned lo = f2bf(W2[(size_t)k * 256 + n]);
        unsigned hi = f2bf(W2[(size_t)(k + 1) * 256 + n]);
        ((unsigned*)W2T)[i] = lo | (hi << 16);
    } else {                                     // WpT [128][256] <- Wp [256][128]
        int i = idx - 131072, e0 = i * 2, n = e0 >> 8, k = e0 & 255;
        unsigned lo = f2bf(Wp[(size_t)k * 128 + n]);
        unsigned hi = f2bf(Wp[(size_t)(k + 1) * 128 + n]);
        ((unsigned*)WpT)[i] = lo | (hi << 16);
    }
}

// ---------------- fused MFMA encoder v3: 32 vocab rows / block, grid 1000 --
// 512 threads = 8 waves; wave w owns a column slice of every GEMM
// (G1: 64 cols, G2: 32 cols, G3: 16 cols). Full-K GEMMs, no chunk loop;
// U (32x512 bf16) lives whole in LDS. 6 barriers per block.
__global__ __launch_bounds__(512, 6) void enc_kernel(
    const float* __restrict__ embed,
    const unsigned short* __restrict__ W1T, const float* __restrict__ b1,
    const unsigned short* __restrict__ W2T, const float* __restrict__ b2,
    const float* __restrict__ gamma, const float* __restrict__ beta,
    const unsigned short* __restrict__ WpT, const float* __restrict__ bp,
    unsigned short* __restrict__ ptab)
{
    __shared__ char sE[32 * 512];      // bf16 [32][256], swizzled (e, then h)
    __shared__ char sU[32 * 1024];     // bf16 [32][512], swizzled U; later p stage
    __shared__ float sPart[32][8][2];
    __shared__ float sMR[32][2];

    const int tid  = threadIdx.x;
    const int lane = tid & 63;
    const int w    = tid >> 6;         // 0..7 column-slice group
    const int l15  = lane & 15;
    const int lk   = lane >> 4;        // 0..3
    const int n0   = blockIdx.x * 32;
    const int swl  = (l15 & 7) << 4;   // A-frag row swizzle (row&7 == l15&7)

    // ---- load E tile: 32 identity rows, f32 -> bf16 swizzled ----
    #pragma unroll
    for (int cc = 0; cc < 2; ++cc) {
        int c = cc * 512 + tid;          // 0..1023 16B-chunks
        int row  = c >> 5;
        int slot = (c & 31) << 4;
        int kbs  = slot ^ ((row & 7) << 4);
        const float* src = embed + (size_t)(n0 + row) * 256 + (kbs >> 1);
        float4 a = *(const float4*)src;
        float4 b = *(const float4*)(src + 4);
        uint4 pk;
        pk.x = (unsigned)f2bf(a.x) | ((unsigned)f2bf(a.y) << 16);
        pk.y = (unsigned)f2bf(a.z) | ((unsigned)f2bf(a.w) << 16);
        pk.z = (unsigned)f2bf(b.x) | ((unsigned)f2bf(b.y) << 16);
        pk.w = (unsigned)f2bf(b.z) | ((unsigned)f2bf(b.w) << 16);
        *(uint4*)(sE + row * 512 + slot) = pk;
    }
    __syncthreads();                                   // B1

    // ---- GEMM1: U = relu(E @ W1 + b1); wave cols [w*64, w*64+64), K=256 ----
    #pragma unroll
    for (int nf2 = 0; nf2 < 2; ++nf2) {
        f32x4 acc1[2][2];
        acc1[0][0] = acc1[0][1] = acc1[1][0] = acc1[1][1] = (f32x4){0.f, 0.f, 0.f, 0.f};
        const char* w1p = (const char*)W1T + (size_t)(w * 64 + nf2 * 32 + l15) * 512 + lk * 16;
        #pragma unroll
        for (int ks = 0; ks < 8; ++ks) {
            int ka = (ks * 64 + lk * 16) ^ swl;
            bf16x8 a0 = *(const bf16x8*)(sE + l15 * 512 + ka);
            bf16x8 a1 = *(const bf16x8*)(sE + (16 + l15) * 512 + ka);
            bf16x8 b0 = *(const bf16x8*)(w1p + ks * 64);
            bf16x8 b1f = *(const bf16x8*)(w1p + 16 * 512 + ks * 64);
            acc1[0][0] = MFMA(a0, b0,  acc1[0][0]);
            acc1[1][0] = MFMA(a1, b0,  acc1[1][0]);
            acc1[0][1] = MFMA(a0, b1f, acc1[0][1]);
            acc1[1][1] = MFMA(a1, b1f, acc1[1][1]);
        }
        float bv0 = b1[w * 64 + nf2 * 32 + l15];
        float bv1 = b1[w * 64 + nf2 * 32 + 16 + l15];
        #pragma unroll
        for (int mi = 0; mi < 2; ++mi)
            #pragma unroll
            for (int nj = 0; nj < 2; ++nj) {
                float bv = nj ? bv1 : bv0;
                #pragma unroll
                for (int r = 0; r < 4; ++r) {
                    int row = mi * 16 + lk * 4 + r;
                    int col = w * 64 + nf2 * 32 + nj * 16 + l15;
                    float v = fmaxf(acc1[mi][nj][r] + bv, 0.f);
                    *(unsigned short*)(sU + row * 1024 + ((col * 2) ^ ((row & 7) << 4))) = f2bf(v);
                }
            }
    }
    __syncthreads();                                   // B2

    // ---- GEMM2: F = U @ W2; wave cols [w*32, w*32+32), K=512 ----
    f32x4 acc2[2][2];
    acc2[0][0] = acc2[0][1] = acc2[1][0] = acc2[1][1] = (f32x4){0.f, 0.f, 0.f, 0.f};
    {
        const char* w2p = (const char*)W2T + (size_t)(w * 32 + l15) * 1024 + lk * 16;
        #pragma unroll 4
        for (int ks = 0; ks < 16; ++ks) {
            int ka = (ks * 64 + lk * 16) ^ swl;
            bf16x8 a0 = *(const bf16x8*)(sU + l15 * 1024 + ka);
            bf16x8 a1 = *(const bf16x8*)(sU + (16 + l15) * 1024 + ka);
            bf16x8 b0 = *(const bf16x8*)(w2p + ks * 64);
            bf16x8 b1f = *(const bf16x8*)(w2p + 16 * 1024 + ks * 64);
            acc2[0][0] = MFMA(a0, b0,  acc2[0][0]);
            acc2[1][0] = MFMA(a1, b0,  acc2[1][0]);
            acc2[0][1] = MFMA(a0, b1f, acc2[0][1]);
            acc2[1][1] = MFMA(a1, b1f, acc2[1][1]);
        }
    }

    // ---- x = e + f + b2 ; LN partials (wave covers 32 cols) ----
    float b2v[2], gv[2], btv[2];
    #pragma unroll
    for (int nj = 0; nj < 2; ++nj) {
        int col = w * 32 + nj * 16 + l15;
        b2v[nj] = b2[col]; gv[nj] = gamma[col]; btv[nj] = beta[col];
    }
    #pragma unroll
    for (int mi = 0; mi < 2; ++mi)
        #pragma unroll
        for (int r = 0; r < 4; ++r) {
            int row = mi * 16 + lk * 4 + r;
            int swr = (row & 7) << 4;
            float s1 = 0.f, s2 = 0.f;
            #pragma unroll
            for (int nj = 0; nj < 2; ++nj) {
                int col = w * 32 + nj * 16 + l15;
                float e = bf2f(*(const unsigned short*)(sE + row * 512 + ((col * 2) ^ swr)));
                float x = acc2[mi][nj][r] + b2v[nj] + e;
                acc2[mi][nj][r] = x;
                s1 += x; s2 = fmaf(x, x, s2);
            }
            s1 += __shfl_xor(s1, 1); s2 += __shfl_xor(s2, 1);
            s1 += __shfl_xor(s1, 2); s2 += __shfl_xor(s2, 2);
            s1 += __shfl_xor(s1, 4); s2 += __shfl_xor(s2, 4);
            s1 += __shfl_xor(s1, 8); s2 += __shfl_xor(s2, 8);
            if (l15 == 0) { sPart[row][w][0] = s1; sPart[row][w][1] = s2; }
        }
    __syncthreads();                                   // B3
    if (tid < 32) {
        float t1 = 0.f, t2 = 0.f;
        #pragma unroll
        for (int ww = 0; ww < 8; ++ww) { t1 += sPart[tid][ww][0]; t2 += sPart[tid][ww][1]; }
        float mu  = t1 * (1.f / 256.f);
        float var = t2 * (1.f / 256.f) - mu * mu;
        sMR[tid][0] = mu;
        sMR[tid][1] = rsqrtf(var + 1e-5f);
    }
    __syncthreads();                                   // B4
    // ---- h -> sE (bf16, swizzled; overwrites e) ----
    #pragma unroll
    for (int mi = 0; mi < 2; ++mi)
        #pragma unroll
        for (int r = 0; r < 4; ++r) {
            int row = mi * 16 + lk * 4 + r;
            int swr = (row & 7) << 4;
            float mu = sMR[row][0], rs = sMR[row][1];
            #pragma unroll
            for (int nj = 0; nj < 2; ++nj) {
                int col = w * 32 + nj * 16 + l15;
                float h = (acc2[mi][nj][r] - mu) * rs * gv[nj] + btv[nj];
                *(unsigned short*)(sE + row * 512 + ((col * 2) ^ swr)) = f2bf(h);
            }
        }
    __syncthreads();                                   // B5

    // ---- GEMM3: p = h @ Wp + bp; wave cols [w*16, w*16+16), K=256 ----
    f32x4 acc3[2];
    acc3[0] = acc3[1] = (f32x4){0.f, 0.f, 0.f, 0.f};
    {
        const char* wpp = (const char*)WpT + (size_t)(w * 16 + l15) * 512 + lk * 16;
        #pragma unroll
        for (int ks = 0; ks < 8; ++ks) {
            int ka = (ks * 64 + lk * 16) ^ swl;
            bf16x8 a0 = *(const bf16x8*)(sE + l15 * 512 + ka);
            bf16x8 a1 = *(const bf16x8*)(sE + (16 + l15) * 512 + ka);
            bf16x8 b0 = *(const bf16x8*)(wpp + ks * 64);
            acc3[0] = MFMA(a0, b0, acc3[0]);
            acc3[1] = MFMA(a1, b0, acc3[1]);
        }
    }
    {
        float bpv = bp[w * 16 + l15];
        #pragma unroll
        for (int mi = 0; mi < 2; ++mi)
            #pragma unroll
            for (int r = 0; r < 4; ++r) {
                int row = mi * 16 + lk * 4 + r;
                int col = w * 16 + l15;
                *(unsigned short*)(sU + row * 256 + col * 2) = f2bf(acc3[mi][r] + bpv);
            }
    }
    __syncthreads();                                   // B6
    {
        int row = tid >> 4, slot = (tid & 15) << 4;    // 512 chunks = 32x512B
        *(uint4*)((char*)ptab + (size_t)(n0 + row) * 256 + slot) =
            *(const uint4*)(sU + row * 256 + slot);
    }
}

// ---------------- sprep v3: Gram + block-inverse + W = (D+L)^-1 K ----------
// One wave per (batch, chunk). Blob out (17408 B/chunk):
//   [0,16384): WTP[d2=64][i=64] u32 = packed bf16 pair (W[i][2d2], W[i][2d2+1])
//   [16384, 16640): diag[64] f32 (d_i = G_ii + eps); rest pad.
__global__ __launch_bounds__(64) void sprep_kernel(
    const int* __restrict__ seq, const unsigned short* __restrict__ ptab,
    char* __restrict__ SBg)
{
    __shared__ unsigned short sK[64 * 136];   // 17408 B, rows 272 B
    __shared__ float sG[10 * 16 * 17];        // 10880 B, block-major [q][r][c]
    __shared__ float sM[4 * 16 * 17];         //  4352 B
    __shared__ float sQ[64];                  //   256 B
    __shared__ float sW[64 * 132];            // 33792 B, rows 528 B

    const int blk  = blockIdx.x;              // 0..2047
    const int b    = blk >> 5, ch = blk & 31;
    const int t_hi = 2047 - (ch << 6);
    const int lane = threadIdx.x;
    const int l15  = lane & 15, lk = lane >> 4;

    // ---- stage K rows (lane = row i, t = t_hi - i); zero the query pad ----
    {
        int t = t_hi - lane;
        if (t == 2047) {
            #pragma unroll
            for (int j = 0; j < 16; ++j)
                *(uint4*)((char*)sK + lane * 272 + j * 16) = (uint4){0u, 0u, 0u, 0u};
        } else {
            int v = seq[b * 2048 + t];
            const char* src = (const char*)(ptab + (size_t)v * 128);
            #pragma unroll
            for (int j = 0; j < 16; ++j)
                *(uint4*)((char*)sK + lane * 272 + j * 16) = *(const uint4*)(src + j * 16);
        }
    }
    __syncthreads();

    // ---- Gram lower blocks via MFMA ----
    f32x4 acc[10];
    #pragma unroll
    for (int q = 0; q < 10; ++q) acc[q] = (f32x4){0.f, 0.f, 0.f, 0.f};
    #pragma unroll
    for (int ks = 0; ks < 4; ++ks) {
        bf16x8 fr[4];
        #pragma unroll
        for (int t4 = 0; t4 < 4; ++t4)
            fr[t4] = *(const bf16x8*)((const char*)sK + (t4 * 16 + l15) * 272 + ks * 64 + lk * 16);
        int q = 0;
        #pragma unroll
        for (int ti = 0; ti < 4; ++ti)
            #pragma unroll
            for (int tj = 0; tj <= ti; ++tj, ++q)
                acc[q] = MFMA(fr[ti], fr[tj], acc[q]);
    }
    {
        int q = 0;
        #pragma unroll
        for (int ti = 0; ti < 4; ++ti)
            #pragma unroll
            for (int tj = 0; tj <= ti; ++tj, ++q)
                #pragma unroll
                for (int r = 0; r < 4; ++r)
                    sG[q * 272 + (lk * 4 + r) * 17 + l15] = acc[q][r];
    }
    __syncthreads();

    // ---- reciprocals of diagonal (lane = (g = lk, row = l15)) ----
    {
        int dq = (lk * (lk + 3)) >> 1;            // diag block q-index
        float d = sG[dq * 272 + l15 * 17 + l15] + 1e-6f;
        sQ[lane] = 1.0f / d;
    }
    __syncthreads();

    // ---- invert 4 diagonal blocks: group g = lk, column c = l15 ----
    {
        const int g = lk, c = l15;
        const float* Tg = &sG[((g * (g + 3)) >> 1) * 272];
        float qv[16], av[16], mcol[16];
        #pragma unroll
        for (int r = 0; r < 16; ++r) { qv[r] = sQ[g * 16 + r]; av[r] = 0.f; }
        #pragma unroll
        for (int r = 0; r < 16; ++r) {
            float mr = (((r == c) ? 1.f : 0.f) - av[r]) * qv[r];
            mcol[r] = mr;
            #pragma unroll
            for (int i = r + 1; i < 16; ++i)
                av[i] = fmaf(Tg[i * 17 + r], mr, av[i]);
        }
        #pragma unroll
        for (int r = 0; r < 16; ++r)
            sM[g * 272 + r * 17 + c] = mcol[r];
    }
    __syncthreads();

    // ---- W build: lane = (rr = l15 row-in-block, dqt = lk d-quarter) ----
    const int rr = l15, dqt = lk;
    #pragma unroll 1
    for (int s = 0; s < 4; ++s) {
        float a[32];
        {   // init from K row 16s+rr, cols [dqt*32, +32)
            const char* kr = (const char*)sK + (16 * s + rr) * 272 + dqt * 64;
            #pragma unroll
            for (int v = 0; v < 4; ++v) {
                uint4 kv = *(const uint4*)(kr + v * 16);
                unpk8(kv, &a[v * 8]);
            }
        }
        #pragma unroll
        for (int j = 0; j < 3; ++j) {           // subtract T_sj @ W_j, j < s
            if (j >= s) break;
            const float* Tb = &sG[(((s * (s + 1)) >> 1) + j) * 272];
            #pragma unroll
            for (int m = 0; m < 16; ++m) {
                float t = Tb[rr * 17 + m];
                const float* wrow = &sW[(16 * j + m) * 132 + dqt * 32];
                #pragma unroll
                for (int v = 0; v < 8; ++v) {
                    f32x4 wv = *(const f32x4*)(wrow + v * 4);
                    a[v * 4 + 0] = fmaf(-t, wv.x, a[v * 4 + 0]);
                    a[v * 4 + 1] = fmaf(-t, wv.y, a[v * 4 + 1]);
                    a[v * 4 + 2] = fmaf(-t, wv.z, a[v * 4 + 2]);
                    a[v * 4 + 3] = fmaf(-t, wv.w, a[v * 4 + 3]);
                }
            }
        }
        {   // write tmp rows of block s
            float* wrow = &sW[(16 * s + rr) * 132 + dqt * 32];
            #pragma unroll
            for (int v = 0; v < 8; ++v) {
                f32x4 wv = {a[v * 4 + 0], a[v * 4 + 1], a[v * 4 + 2], a[v * 4 + 3]};
                *(f32x4*)(wrow + v * 4) = wv;
            }
        }
        __syncthreads();
        float o[32];
        #pragma unroll
        for (int v = 0; v < 32; ++v) o[v] = 0.f;
        #pragma unroll
        for (int cc = 0; cc < 16; ++cc) {       // W_s = M_s @ tmp
            float mm = sM[s * 272 + rr * 17 + cc];
            const float* wrow = &sW[(16 * s + cc) * 132 + dqt * 32];
            #pragma unroll
            for (int v = 0; v < 8; ++v) {
                f32x4 wv = *(const f32x4*)(wrow + v * 4);
                o[v * 4 + 0] = fmaf(mm, wv.x, o[v * 4 + 0]);
                o[v * 4 + 1] = fmaf(mm, wv.y, o[v * 4 + 1]);
                o[v * 4 + 2] = fmaf(mm, wv.z, o[v * 4 + 2]);
                o[v * 4 + 3] = fmaf(mm, wv.w, o[v * 4 + 3]);
            }
        }
        __syncthreads();                        // all tmp reads done
        {   // overwrite block-s rows with final W_s
            float* wrow = &sW[(16 * s + rr) * 132 + dqt * 32];
            #pragma unroll
            for (int v = 0; v < 8; ++v) {
                f32x4 wv = {o[v * 4 + 0], o[v * 4 + 1], o[v * 4 + 2], o[v * 4 + 3]};
                *(f32x4*)(wrow + v * 4) = wv;
            }
        }
        __syncthreads();
    }

    // ---- write WTP (transposed, packed bf16) + diag ----
    char* blob = SBg + (size_t)blk * 17408;
    unsigned* wtp = (unsigned*)blob;
    #pragma unroll 8
    for (int d2 = 0; d2 < 64; ++d2) {
        float2 wv = *(const float2*)&sW[lane * 132 + d2 * 2];
        wtp[d2 * 64 + lane] = (unsigned)f2bf(wv.x) | ((unsigned)f2bf(wv.y) << 16);
    }
    {
        int dq = (lk * (lk + 3)) >> 1;
        float d = sG[dq * 272 + l15 * 17 + l15] + 1e-6f;
        *(float*)(blob + 16384 + lane * 4) = d;
    }
}

// ---------------- serial chunked scan v2: 8-wave cooperative chunk body ----
// 512 threads / block, one block per batch. Raw s_barrier only (no
// __syncthreads in the loop: it would drain vmcnt and kill the DMA
// double-buffer). u lives in registers (pair per lane, replicated per wave).
__global__ __launch_bounds__(512) void scan_kernel(
    const int* __restrict__ seq, const unsigned short* __restrict__ ptab,
    const char* __restrict__ SBg, const float* __restrict__ zrow,
    float* __restrict__ csb)
{
    __shared__ int sSeq[2048];
    __shared__ unsigned short sKb[2][8192];      // [64][128] bf16, linear
    __shared__ __align__(16) char sBlob[2][16640]; // WTP 16K + diag 256B
    __shared__ float  sPZ[8][64];                // per-wave z partials
    __shared__ float2 sPC[8][64];                // per-wave du partials / csv

    const int b    = blockIdx.x;
    const int tid  = threadIdx.x;
    const int lane = tid & 63;
    const int w    = tid >> 6;

    *(int4*)&sSeq[tid * 4] = *(const int4*)&seq[b * 2048 + tid * 4];
    float u0, u1;                                // u pair (2*lane, 2*lane+1)
    {
        int vq = seq[b * 2048 + 2047];
        unsigned pk = *(const unsigned*)(ptab + (size_t)vq * 128 + lane * 2);
        u0 = bf2f((unsigned short)(pk & 0xffff));
        u1 = bf2f((unsigned short)(pk >> 16));
    }
    float csv0 = 0.f, csv1 = 0.f;
    __syncthreads();            // once: sSeq visible (drains vmcnt, harmless here)

    auto STAGE = [&](int s, int ch) {            // 4 GLLs/wave (wave 7: 5)
        int t_hi = 2047 - (ch << 6);
        #pragma unroll
        for (int kk = 0; kk < 2; ++kk) {
            int k = w * 2 + kk;
            int g = k * 64 + lane;
            int r = g >> 4, sd = g & 15;
            int t = t_hi - r;
            int v = sSeq[t];
            const char* srow = (t == 2047) ? (const char*)zrow
                                           : (const char*)(ptab + (size_t)v * 128);
            GLL16(srow + sd * 16, (char*)sKb[s] + k * 1024);
        }
        const char* bsrc = SBg + ((size_t)b * 32 + ch) * 17408;
        #pragma unroll
        for (int kk = 0; kk < 2; ++kk) {
            int k = w * 2 + kk;
            GLL16(bsrc + k * 1024 + lane * 16, (char*)sBlob[s] + k * 1024);
        }
        if (w == 7)
            GLL4(bsrc + 16384 + lane * 4, (char*)sBlob[s] + 16384);
    };

    STAGE(0, 0); STAGE(1, 1);

    #pragma unroll 1
    for (int c = 0; c < 32; ++c) {
        const int cur = c & 1;
        if (c < 31) {
            if (w == 7) asm volatile("s_waitcnt vmcnt(5)" ::: "memory");
            else        asm volatile("s_waitcnt vmcnt(4)" ::: "memory");
        } else {
            asm volatile("s_waitcnt vmcnt(0)" ::: "memory");
        }
        __builtin_amdgcn_s_barrier();            // B0: all waves' DMA landed
        __builtin_amdgcn_sched_barrier(0);

        const unsigned short* kb = sKb[cur];
        const unsigned* wt = (const unsigned*)(sBlob[cur]);
        const float* dgv = (const float*)(sBlob[cur] + 16384);

        // phase Z partial: wave w covers d2 in [8w, 8w+8); lane = i
        float zp = 0.f;
        #pragma unroll
        for (int j = 0; j < 8; ++j) {
            int d2 = w * 8 + j;
            unsigned wp = wt[d2 * 64 + lane];    // conflict-free
            float ua = __shfl(u0, d2);
            float ub = __shfl(u1, d2);
            zp = fmaf(bf2f((unsigned short)(wp & 0xffff)), ua, zp);
            zp = fmaf(bf2f((unsigned short)(wp >> 16)),    ub, zp);
        }
        sPZ[w][lane] = zp;
        asm volatile("s_waitcnt lgkmcnt(0)" ::: "memory");
        __builtin_amdgcn_s_barrier();            // B1
        __builtin_amdgcn_sched_barrier(0);

        // redundant full reduce (identical order in every wave) -> z, ci
        float z = 0.f;
        #pragma unroll
        for (int ww = 0; ww < 8; ++ww) z += sPZ[ww][lane];
        float ci = z * dgv[lane];

        // phase C partial: wave w covers i in [8w, 8w+8); lane = d-pair
        float du0 = 0.f, du1 = 0.f;
        #pragma unroll
        for (int j = 0; j < 8; ++j) {
            int i = w * 8 + j;
            float zi  = __shfl(z, i);
            float cii = __shfl(ci, i);
            unsigned kp = *(const unsigned*)((const char*)kb + i * 256 + lane * 4);
            float k0 = bf2f((unsigned short)(kp & 0xffff));
            float k1 = bf2f((unsigned short)(kp >> 16));
            du0  = fmaf(zi,  k0, du0);  du1  = fmaf(zi,  k1, du1);
            csv0 = fmaf(cii, k0, csv0); csv1 = fmaf(cii, k1, csv1);
        }
        sPC[w][lane] = make_float2(du0, du1);
        asm volatile("s_waitcnt lgkmcnt(0)" ::: "memory");
        __builtin_amdgcn_s_barrier();            // B2: buf cur fully consumed
        __builtin_amdgcn_sched_barrier(0);

        if (c + 2 < 32) STAGE(cur, c + 2);       // overwrite is now safe

        float s0 = 0.f, s1 = 0.f;
        #pragma unroll
        for (int ww = 0; ww < 8; ++ww) {
            float2 p = sPC[ww][lane];
            s0 += p.x; s1 += p.y;
        }
        u0 -= s0; u1 -= s1;
    }

    // final csv reduce across waves
    asm volatile("s_waitcnt lgkmcnt(0)" ::: "memory");
    __builtin_amdgcn_s_barrier();                // all u-update reads done
    sPC[w][lane] = make_float2(csv0, csv1);
    asm volatile("s_waitcnt lgkmcnt(0)" ::: "memory");
    __builtin_amdgcn_s_barrier();
    if (w == 0) {
        float a0 = 0.f, a1 = 0.f;
        #pragma unroll
        for (int ww = 0; ww < 8; ++ww) {
            float2 p = sPC[ww][lane];
            a0 += p.x; a1 += p.y;
        }
        csb[b * 128 + lane * 2]     = a0;
        csb[b * 128 + lane * 2 + 1] = a1;
    }
}

// ---------------- out = cs @ Wo + bo : [64,128]@[128,32000] ----------------
__global__ __launch_bounds__(256) void out_kernel(
    const float* __restrict__ cs, const float* __restrict__ Wo,
    const float* __restrict__ bo, float* __restrict__ out)
{
    __shared__ float sC[64 * 128];
    const int tid = threadIdx.x;
    #pragma unroll
    for (int r = 0; r < 8; ++r)
        ((float4*)sC)[r * 256 + tid] = ((const float4*)cs)[r * 256 + tid];
    __syncthreads();

    const int j = blockIdx.x * 256 + tid;
    float acc[64];
    #pragma unroll
    for (int r = 0; r < 64; ++r) acc[r] = 0.f;
    for (int k0 = 0; k0 < 128; k0 += 4) {
        float w0 = Wo[(size_t)(k0 + 0) * Vv + j];
        float w1 = Wo[(size_t)(k0 + 1) * Vv + j];
        float w2 = Wo[(size_t)(k0 + 2) * Vv + j];
        float w3 = Wo[(size_t)(k0 + 3) * Vv + j];
        #pragma unroll
        for (int r = 0; r < 64; ++r) {
            float4 c = *(const float4*)&sC[r * 128 + k0];
            acc[r] = fmaf(c.x, w0, fmaf(c.y, w1, fmaf(c.z, w2, fmaf(c.w, w3, acc[r]))));
        }
    }
    float bj = bo[j];
    #pragma unroll
    for (int r = 0; r < 64; ++r)
        out[(size_t)r * Vv + j] = acc[r] + bj;
}

extern "C" void kernel_launch(void* const* d_in, const int* in_sizes, int n_in,
                              void* d_out, int out_size, void* d_ws, size_t ws_size,
                              hipStream_t stream)
{
    const int*   seq   = (const int*)  d_in[0];
    const float* embed = (const float*)d_in[1];
    const float* W1    = (const float*)d_in[2];
    const float* b1    = (const float*)d_in[3];
    const float* W2    = (const float*)d_in[4];
    const float* b2    = (const float*)d_in[5];
    const float* gamma = (const float*)d_in[6];
    const float* beta  = (const float*)d_in[7];
    const float* Wp    = (const float*)d_in[8];
    const float* bp    = (const float*)d_in[9];
    const float* Wo    = (const float*)d_in[10];
    const float* bo    = (const float*)d_in[11];
    float* out = (float*)d_out;

    char* wsb = (char*)d_ws;
    unsigned short* ptab = (unsigned short*)(wsb);                 //  8,192,000 B
    char*           SBg  = wsb + 8192000;                          // 35,651,584 B
    unsigned short* W1T  = (unsigned short*)(wsb + 43843584);      //    262,144 B
    unsigned short* W2T  = (unsigned short*)(wsb + 44105728);      //    262,144 B
    unsigned short* WpT  = (unsigned short*)(wsb + 44367872);      //     65,536 B
    float*          csb  = (float*)(wsb + 44433408);               //     32,768 B
    float*          zrow = (float*)(wsb + 44466176);               //        256 B

    prep_kernel<<<576, 256, 0, stream>>>(W1, W2, Wp, W1T, W2T, WpT, zrow);
    enc_kernel<<<Vv / 32, 512, 0, stream>>>(embed, W1T, b1, W2T, b2,
                                            gamma, beta, WpT, bp, ptab);
    sprep_kernel<<<2048, 64, 0, stream>>>(seq, ptab, SBg);
    scan_kernel<<<64, 512, 0, stream>>>(seq, ptab, SBg, zrow, csb);
    out_kernel<<<Vv / 256, 256, 0, stream>>>(csb, Wo, bo, out);
}

// Round 10
// 249.621 us; speedup vs baseline: 1.1271x; 1.1271x over previous
//
#include <hip/hip_runtime.h>

#define Vv 32000
#define Ll 2048

typedef __bf16 bf16x8 __attribute__((ext_vector_type(8)));
typedef float  f32x4  __attribute__((ext_vector_type(4)));

__device__ __forceinline__ unsigned short f2bf(float f) {
    unsigned u = __builtin_bit_cast(unsigned, f);
    u += 0x7fffu + ((u >> 16) & 1u);
    return (unsigned short)(u >> 16);
}
__device__ __forceinline__ float bf2f(unsigned short s) {
    unsigned u = (unsigned)s << 16;
    return __builtin_bit_cast(float, u);
}
__device__ __forceinline__ void unpk8(uint4 v, float* o) {
    o[0] = bf2f((unsigned short)(v.x & 0xffff)); o[1] = bf2f((unsigned short)(v.x >> 16));
    o[2] = bf2f((unsigned short)(v.y & 0xffff)); o[3] = bf2f((unsigned short)(v.y >> 16));
    o[4] = bf2f((unsigned short)(v.z & 0xffff)); o[5] = bf2f((unsigned short)(v.z >> 16));
    o[6] = bf2f((unsigned short)(v.w & 0xffff)); o[7] = bf2f((unsigned short)(v.w >> 16));
}

#define MFMA(a, b, c) __builtin_amdgcn_mfma_f32_16x16x32_bf16(a, b, c, 0, 0, 0)
#define GLL16(gsrc, ldst)                                                    \
    __builtin_amdgcn_global_load_lds(                                        \
        (const __attribute__((address_space(1))) void*)(gsrc),               \
        (__attribute__((address_space(3))) void*)(ldst), 16, 0, 0)
#define GLL4(gsrc, ldst)                                                     \
    __builtin_amdgcn_global_load_lds(                                        \
        (const __attribute__((address_space(1))) void*)(gsrc),               \
        (__attribute__((address_space(3))) void*)(ldst), 4, 0, 0)

// ---------------- prep: transpose W1/W2/Wp to bf16 [N][K]; zero pad row ----
__global__ __launch_bounds__(256) void prep_kernel(
    const float* __restrict__ W1, const float* __restrict__ W2,
    const float* __restrict__ Wp, unsigned short* __restrict__ W1T,
    unsigned short* __restrict__ W2T, unsigned short* __restrict__ WpT,
    float* __restrict__ zrow)
{
    int idx = blockIdx.x * 256 + threadIdx.x;   // pair index
    if (blockIdx.x == 575 && threadIdx.x < 64) zrow[threadIdx.x] = 0.f;
    if (idx < 65536) {                           // W1T [512][256] <- W1 [256][512]
        int e0 = idx * 2, n = e0 >> 8, k = e0 & 255;
        unsigned lo = f2bf(W1[(size_t)k * 512 + n]);
        unsigned hi = f2bf(W1[(size_t)(k + 1) * 512 + n]);
        ((unsigned*)W1T)[idx] = lo | (hi << 16);
    } else if (idx < 131072) {                   // W2T [256][512] <- W2 [512][256]
        int i = idx - 65536, e0 = i * 2, n = e0 >> 9, k = e0 & 511;
        unsigned lo = f2bf(W2[(size_t)k * 256 + n]);
        unsigned hi = f2bf(W2[(size_t)(k + 1) * 256 + n]);
        ((unsigned*)W2T)[i] = lo | (hi << 16);
    } else {                                     // WpT [128][256] <- Wp [256][128]
        int i = idx - 131072, e0 = i * 2, n = e0 >> 8, k = e0 & 255;
        unsigned lo = f2bf(Wp[(size_t)k * 128 + n]);
        unsigned hi = f2bf(Wp[(size_t)(k + 1) * 128 + n]);
        ((unsigned*)WpT)[i] = lo | (hi << 16);
    }
}

// ---------------- fused MFMA encoder v4: 32 vocab rows / block, grid 1000 --
// 512 threads = 8 waves; wave w owns a column slice of every GEMM.
// B-fragments batch-prefetched into registers (16 loads -> one wait).
__global__ __launch_bounds__(512, 4) void enc_kernel(
    const float* __restrict__ embed,
    const unsigned short* __restrict__ W1T, const float* __restrict__ b1,
    const unsigned short* __restrict__ W2T, const float* __restrict__ b2,
    const float* __restrict__ gamma, const float* __restrict__ beta,
    const unsigned short* __restrict__ WpT, const float* __restrict__ bp,
    unsigned short* __restrict__ ptab)
{
    __shared__ char sE[32 * 512];      // bf16 [32][256], swizzled (e, then h)
    __shared__ char sU[32 * 1024];     // bf16 [32][512], swizzled U; later p stage
    __shared__ float sPart[32][8][2];
    __shared__ float sMR[32][2];

    const int tid  = threadIdx.x;
    const int lane = tid & 63;
    const int w    = tid >> 6;         // 0..7 column-slice group
    const int l15  = lane & 15;
    const int lk   = lane >> 4;        // 0..3
    const int n0   = blockIdx.x * 32;
    const int swl  = (l15 & 7) << 4;   // A-frag row swizzle (row&7 == l15&7)

    // ---- load E tile: 32 identity rows, f32 -> bf16 swizzled ----
    #pragma unroll
    for (int cc = 0; cc < 2; ++cc) {
        int c = cc * 512 + tid;          // 0..1023 16B-chunks
        int row  = c >> 5;
        int slot = (c & 31) << 4;
        int kbs  = slot ^ ((row & 7) << 4);
        const float* src = embed + (size_t)(n0 + row) * 256 + (kbs >> 1);
        float4 a = *(const float4*)src;
        float4 b = *(const float4*)(src + 4);
        uint4 pk;
        pk.x = (unsigned)f2bf(a.x) | ((unsigned)f2bf(a.y) << 16);
        pk.y = (unsigned)f2bf(a.z) | ((unsigned)f2bf(a.w) << 16);
        pk.z = (unsigned)f2bf(b.x) | ((unsigned)f2bf(b.y) << 16);
        pk.w = (unsigned)f2bf(b.z) | ((unsigned)f2bf(b.w) << 16);
        *(uint4*)(sE + row * 512 + slot) = pk;
    }
    __syncthreads();                                   // B1

    // ---- GEMM1: U = relu(E @ W1 + b1); wave cols [w*64, w*64+64), K=256 ----
    #pragma unroll
    for (int nf2 = 0; nf2 < 2; ++nf2) {
        f32x4 acc1[2][2];
        acc1[0][0] = acc1[0][1] = acc1[1][0] = acc1[1][1] = (f32x4){0.f, 0.f, 0.f, 0.f};
        const char* w1p = (const char*)W1T + (size_t)(w * 64 + nf2 * 32 + l15) * 512 + lk * 16;
        bf16x8 bfr[16];                 // batch-prefetch all B fragments
        #pragma unroll
        for (int ks = 0; ks < 8; ++ks) {
            bfr[ks * 2]     = *(const bf16x8*)(w1p + ks * 64);
            bfr[ks * 2 + 1] = *(const bf16x8*)(w1p + 16 * 512 + ks * 64);
        }
        #pragma unroll
        for (int ks = 0; ks < 8; ++ks) {
            int ka = (ks * 64 + lk * 16) ^ swl;
            bf16x8 a0 = *(const bf16x8*)(sE + l15 * 512 + ka);
            bf16x8 a1 = *(const bf16x8*)(sE + (16 + l15) * 512 + ka);
            acc1[0][0] = MFMA(a0, bfr[ks * 2],     acc1[0][0]);
            acc1[1][0] = MFMA(a1, bfr[ks * 2],     acc1[1][0]);
            acc1[0][1] = MFMA(a0, bfr[ks * 2 + 1], acc1[0][1]);
            acc1[1][1] = MFMA(a1, bfr[ks * 2 + 1], acc1[1][1]);
        }
        float bv0 = b1[w * 64 + nf2 * 32 + l15];
        float bv1 = b1[w * 64 + nf2 * 32 + 16 + l15];
        #pragma unroll
        for (int mi = 0; mi < 2; ++mi)
            #pragma unroll
            for (int nj = 0; nj < 2; ++nj) {
                float bv = nj ? bv1 : bv0;
                #pragma unroll
                for (int r = 0; r < 4; ++r) {
                    int row = mi * 16 + lk * 4 + r;
                    int col = w * 64 + nf2 * 32 + nj * 16 + l15;
                    float v = fmaxf(acc1[mi][nj][r] + bv, 0.f);
                    *(unsigned short*)(sU + row * 1024 + ((col * 2) ^ ((row & 7) << 4))) = f2bf(v);
                }
            }
    }
    __syncthreads();                                   // B2

    // ---- GEMM2: F = U @ W2; wave cols [w*32, w*32+32), K=512, 2 halves ----
    f32x4 acc2[2][2];
    acc2[0][0] = acc2[0][1] = acc2[1][0] = acc2[1][1] = (f32x4){0.f, 0.f, 0.f, 0.f};
    {
        const char* w2p = (const char*)W2T + (size_t)(w * 32 + l15) * 1024 + lk * 16;
        #pragma unroll
        for (int h = 0; h < 2; ++h) {
            bf16x8 bfr[16];
            #pragma unroll
            for (int ks = 0; ks < 8; ++ks) {
                int kss = h * 8 + ks;
                bfr[ks * 2]     = *(const bf16x8*)(w2p + kss * 64);
                bfr[ks * 2 + 1] = *(const bf16x8*)(w2p + 16 * 1024 + kss * 64);
            }
            #pragma unroll
            for (int ks = 0; ks < 8; ++ks) {
                int kss = h * 8 + ks;
                int ka = (kss * 64 + lk * 16) ^ swl;
                bf16x8 a0 = *(const bf16x8*)(sU + l15 * 1024 + ka);
                bf16x8 a1 = *(const bf16x8*)(sU + (16 + l15) * 1024 + ka);
                acc2[0][0] = MFMA(a0, bfr[ks * 2],     acc2[0][0]);
                acc2[1][0] = MFMA(a1, bfr[ks * 2],     acc2[1][0]);
                acc2[0][1] = MFMA(a0, bfr[ks * 2 + 1], acc2[0][1]);
                acc2[1][1] = MFMA(a1, bfr[ks * 2 + 1], acc2[1][1]);
            }
        }
    }

    // ---- x = e + f + b2 ; LN partials (wave covers 32 cols) ----
    float b2v[2], gv[2], btv[2];
    #pragma unroll
    for (int nj = 0; nj < 2; ++nj) {
        int col = w * 32 + nj * 16 + l15;
        b2v[nj] = b2[col]; gv[nj] = gamma[col]; btv[nj] = beta[col];
    }
    #pragma unroll
    for (int mi = 0; mi < 2; ++mi)
        #pragma unroll
        for (int r = 0; r < 4; ++r) {
            int row = mi * 16 + lk * 4 + r;
            int swr = (row & 7) << 4;
            float s1 = 0.f, s2 = 0.f;
            #pragma unroll
            for (int nj = 0; nj < 2; ++nj) {
                int col = w * 32 + nj * 16 + l15;
                float e = bf2f(*(const unsigned short*)(sE + row * 512 + ((col * 2) ^ swr)));
                float x = acc2[mi][nj][r] + b2v[nj] + e;
                acc2[mi][nj][r] = x;
                s1 += x; s2 = fmaf(x, x, s2);
            }
            s1 += __shfl_xor(s1, 1); s2 += __shfl_xor(s2, 1);
            s1 += __shfl_xor(s1, 2); s2 += __shfl_xor(s2, 2);
            s1 += __shfl_xor(s1, 4); s2 += __shfl_xor(s2, 4);
            s1 += __shfl_xor(s1, 8); s2 += __shfl_xor(s2, 8);
            if (l15 == 0) { sPart[row][w][0] = s1; sPart[row][w][1] = s2; }
        }
    __syncthreads();                                   // B3
    if (tid < 32) {
        float t1 = 0.f, t2 = 0.f;
        #pragma unroll
        for (int ww = 0; ww < 8; ++ww) { t1 += sPart[tid][ww][0]; t2 += sPart[tid][ww][1]; }
        float mu  = t1 * (1.f / 256.f);
        float var = t2 * (1.f / 256.f) - mu * mu;
        sMR[tid][0] = mu;
        sMR[tid][1] = rsqrtf(var + 1e-5f);
    }
    __syncthreads();                                   // B4
    // ---- h -> sE (bf16, swizzled; overwrites e) ----
    #pragma unroll
    for (int mi = 0; mi < 2; ++mi)
        #pragma unroll
        for (int r = 0; r < 4; ++r) {
            int row = mi * 16 + lk * 4 + r;
            int swr = (row & 7) << 4;
            float mu = sMR[row][0], rs = sMR[row][1];
            #pragma unroll
            for (int nj = 0; nj < 2; ++nj) {
                int col = w * 32 + nj * 16 + l15;
                float h = (acc2[mi][nj][r] - mu) * rs * gv[nj] + btv[nj];
                *(unsigned short*)(sE + row * 512 + ((col * 2) ^ swr)) = f2bf(h);
            }
        }
    __syncthreads();                                   // B5

    // ---- GEMM3: p = h @ Wp + bp; wave cols [w*16, w*16+16), K=256 ----
    f32x4 acc3[2];
    acc3[0] = acc3[1] = (f32x4){0.f, 0.f, 0.f, 0.f};
    {
        const char* wpp = (const char*)WpT + (size_t)(w * 16 + l15) * 512 + lk * 16;
        bf16x8 bfr[8];
        #pragma unroll
        for (int ks = 0; ks < 8; ++ks)
            bfr[ks] = *(const bf16x8*)(wpp + ks * 64);
        #pragma unroll
        for (int ks = 0; ks < 8; ++ks) {
            int ka = (ks * 64 + lk * 16) ^ swl;
            bf16x8 a0 = *(const bf16x8*)(sE + l15 * 512 + ka);
            bf16x8 a1 = *(const bf16x8*)(sE + (16 + l15) * 512 + ka);
            acc3[0] = MFMA(a0, bfr[ks], acc3[0]);
            acc3[1] = MFMA(a1, bfr[ks], acc3[1]);
        }
    }
    {
        float bpv = bp[w * 16 + l15];
        #pragma unroll
        for (int mi = 0; mi < 2; ++mi)
            #pragma unroll
            for (int r = 0; r < 4; ++r) {
                int row = mi * 16 + lk * 4 + r;
                int col = w * 16 + l15;
                *(unsigned short*)(sU + row * 256 + col * 2) = f2bf(acc3[mi][r] + bpv);
            }
    }
    __syncthreads();                                   // B6
    {
        int row = tid >> 4, slot = (tid & 15) << 4;    // 512 chunks = 32x512B
        *(uint4*)((char*)ptab + (size_t)(n0 + row) * 256 + slot) =
            *(const uint4*)(sU + row * 256 + slot);
    }
}

// ---------------- sprep v4: 256 threads / chunk; Gram + W = (D+L)^-1 K ----
// Blob out (17408 B/chunk): WTP[d2=64][i=64] packed bf16 pairs + diag f32.
__global__ __launch_bounds__(256) void sprep_kernel(
    const int* __restrict__ seq, const unsigned short* __restrict__ ptab,
    char* __restrict__ SBg)
{
    __shared__ unsigned short sK[64 * 136];   // 17408 B, rows 272 B
    __shared__ float sG[10 * 16 * 17];        // 10880 B, block-major [q][r][c]
    __shared__ float sM[4 * 16 * 17];         //  4352 B
    __shared__ float sQ[64];                  //   256 B
    __shared__ float sW[64 * 132];            // 33792 B, rows 528 B

    const int blk  = blockIdx.x;              // 0..2047
    const int b    = blk >> 5, ch = blk & 31;
    const int t_hi = 2047 - (ch << 6);
    const int tid  = threadIdx.x;
    const int lane = tid & 63;
    const int wv   = tid >> 6;                // 0..3
    const int l15  = lane & 15, lk = lane >> 4;

    // ---- stage K rows: 1024 16B-chunks over 256 threads ----
    #pragma unroll
    for (int i = 0; i < 4; ++i) {
        int c = i * 256 + tid;
        int row = c >> 4, j = c & 15;
        int t = t_hi - row;
        if (t == 2047) {
            *(uint4*)((char*)sK + row * 272 + j * 16) = (uint4){0u, 0u, 0u, 0u};
        } else {
            int v = seq[b * 2048 + t];
            *(uint4*)((char*)sK + row * 272 + j * 16) =
                *(const uint4*)((const char*)(ptab + (size_t)v * 128) + j * 16);
        }
    }
    __syncthreads();

    // ---- Gram lower blocks via MFMA, tiles distributed across 4 waves ----
    {
        int q = 0;
        #pragma unroll
        for (int ti = 0; ti < 4; ++ti)
            #pragma unroll
            for (int tj = 0; tj <= ti; ++tj, ++q) {
                if ((q & 3) != wv) continue;           // wave-uniform branch
                f32x4 acc = (f32x4){0.f, 0.f, 0.f, 0.f};
                #pragma unroll
                for (int ks = 0; ks < 4; ++ks) {
                    bf16x8 fa = *(const bf16x8*)((const char*)sK + (ti * 16 + l15) * 272 + ks * 64 + lk * 16);
                    bf16x8 fb = *(const bf16x8*)((const char*)sK + (tj * 16 + l15) * 272 + ks * 64 + lk * 16);
                    acc = MFMA(fa, fb, acc);
                }
                #pragma unroll
                for (int r = 0; r < 4; ++r)
                    sG[q * 272 + (lk * 4 + r) * 17 + l15] = acc[r];
            }
    }
    __syncthreads();

    // ---- reciprocals of diagonal ----
    if (tid < 64) {
        int dq = (lk * (lk + 3)) >> 1;
        float d = sG[dq * 272 + l15 * 17 + l15] + 1e-6f;
        sQ[tid] = 1.0f / d;
    }
    __syncthreads();

    // ---- invert 4 diagonal blocks (tid<64: g = lk, column c = l15) ----
    if (tid < 64) {
        const int g = lk, c = l15;
        const float* Tg = &sG[((g * (g + 3)) >> 1) * 272];
        float qv[16], av[16], mcol[16];
        #pragma unroll
        for (int r = 0; r < 16; ++r) { qv[r] = sQ[g * 16 + r]; av[r] = 0.f; }
        #pragma unroll
        for (int r = 0; r < 16; ++r) {
            float mr = (((r == c) ? 1.f : 0.f) - av[r]) * qv[r];
            mcol[r] = mr;
            #pragma unroll
            for (int i = r + 1; i < 16; ++i)
                av[i] = fmaf(Tg[i * 17 + r], mr, av[i]);
        }
        #pragma unroll
        for (int r = 0; r < 16; ++r)
            sM[g * 272 + r * 17 + c] = mcol[r];
    }
    __syncthreads();

    // ---- W build: thread = (rr = tid&15 row-in-block, dq8 = tid>>4: 8 cols) ----
    const int rr = tid & 15, dq8 = tid >> 4;
    #pragma unroll 1
    for (int s = 0; s < 4; ++s) {
        float a[8];
        {   // init from K row 16s+rr, cols [dq8*8, +8)
            uint4 kv = *(const uint4*)((const char*)sK + (16 * s + rr) * 272 + dq8 * 16);
            unpk8(kv, a);
        }
        #pragma unroll
        for (int j = 0; j < 3; ++j) {           // subtract T_sj @ W_j, j < s
            if (j >= s) break;
            const float* Tb = &sG[(((s * (s + 1)) >> 1) + j) * 272];
            #pragma unroll
            for (int m = 0; m < 16; ++m) {
                float t = Tb[rr * 17 + m];
                const float* wrow = &sW[(16 * j + m) * 132 + dq8 * 8];
                f32x4 w0 = *(const f32x4*)(wrow);
                f32x4 w1 = *(const f32x4*)(wrow + 4);
                a[0] = fmaf(-t, w0.x, a[0]); a[1] = fmaf(-t, w0.y, a[1]);
                a[2] = fmaf(-t, w0.z, a[2]); a[3] = fmaf(-t, w0.w, a[3]);
                a[4] = fmaf(-t, w1.x, a[4]); a[5] = fmaf(-t, w1.y, a[5]);
                a[6] = fmaf(-t, w1.z, a[6]); a[7] = fmaf(-t, w1.w, a[7]);
            }
        }
        {   // write tmp rows of block s
            float* wrow = &sW[(16 * s + rr) * 132 + dq8 * 8];
            *(f32x4*)(wrow)     = (f32x4){a[0], a[1], a[2], a[3]};
            *(f32x4*)(wrow + 4) = (f32x4){a[4], a[5], a[6], a[7]};
        }
        __syncthreads();
        float o[8];
        #pragma unroll
        for (int v = 0; v < 8; ++v) o[v] = 0.f;
        #pragma unroll
        for (int cc = 0; cc < 16; ++cc) {       // W_s = M_s @ tmp
            float mm = sM[s * 272 + rr * 17 + cc];
            const float* wrow = &sW[(16 * s + cc) * 132 + dq8 * 8];
            f32x4 w0 = *(const f32x4*)(wrow);
            f32x4 w1 = *(const f32x4*)(wrow + 4);
            o[0] = fmaf(mm, w0.x, o[0]); o[1] = fmaf(mm, w0.y, o[1]);
            o[2] = fmaf(mm, w0.z, o[2]); o[3] = fmaf(mm, w0.w, o[3]);
            o[4] = fmaf(mm, w1.x, o[4]); o[5] = fmaf(mm, w1.y, o[5]);
            o[6] = fmaf(mm, w1.z, o[6]); o[7] = fmaf(mm, w1.w, o[7]);
        }
        __syncthreads();                        // all tmp reads done
        {   // overwrite block-s rows with final W_s
            float* wrow = &sW[(16 * s + rr) * 132 + dq8 * 8];
            *(f32x4*)(wrow)     = (f32x4){o[0], o[1], o[2], o[3]};
            *(f32x4*)(wrow + 4) = (f32x4){o[4], o[5], o[6], o[7]};
        }
        __syncthreads();
    }

    // ---- write WTP (transposed, packed bf16) + diag ----
    char* blob = SBg + (size_t)blk * 17408;
    unsigned* wtp = (unsigned*)blob;
    {
        int i = tid & 63;
        #pragma unroll
        for (int dg = 0; dg < 16; ++dg) {
            int d2 = (tid >> 6) * 16 + dg;
            float2 wvp = *(const float2*)&sW[i * 132 + d2 * 2];
            wtp[d2 * 64 + i] = (unsigned)f2bf(wvp.x) | ((unsigned)f2bf(wvp.y) << 16);
        }
    }
    if (tid < 64) {
        int dq = (lk * (lk + 3)) >> 1;
        float d = sG[dq * 272 + l15 * 17 + l15] + 1e-6f;
        *(float*)(blob + 16384 + tid * 4) = d;
    }
}

// ---------------- serial chunked scan v2: 8-wave cooperative chunk body ----
__global__ __launch_bounds__(512) void scan_kernel(
    const int* __restrict__ seq, const unsigned short* __restrict__ ptab,
    const char* __restrict__ SBg, const float* __restrict__ zrow,
    float* __restrict__ csb)
{
    __shared__ int sSeq[2048];
    __shared__ unsigned short sKb[2][8192];      // [64][128] bf16, linear
    __shared__ __align__(16) char sBlob[2][16640]; // WTP 16K + diag 256B
    __shared__ float  sPZ[8][64];                // per-wave z partials
    __shared__ float2 sPC[8][64];                // per-wave du partials / csv

    const int b    = blockIdx.x;
    const int tid  = threadIdx.x;
    const int lane = tid & 63;
    const int w    = tid >> 6;

    *(int4*)&sSeq[tid * 4] = *(const int4*)&seq[b * 2048 + tid * 4];
    float u0, u1;                                // u pair (2*lane, 2*lane+1)
    {
        int vq = seq[b * 2048 + 2047];
        unsigned pk = *(const unsigned*)(ptab + (size_t)vq * 128 + lane * 2);
        u0 = bf2f((unsigned short)(pk & 0xffff));
        u1 = bf2f((unsigned short)(pk >> 16));
    }
    float csv0 = 0.f, csv1 = 0.f;
    __syncthreads();            // once: sSeq visible (drains vmcnt, harmless here)

    auto STAGE = [&](int s, int ch) {            // 4 GLLs/wave (wave 7: 5)
        int t_hi = 2047 - (ch << 6);
        #pragma unroll
        for (int kk = 0; kk < 2; ++kk) {
            int k = w * 2 + kk;
            int g = k * 64 + lane;
            int r = g >> 4, sd = g & 15;
            int t = t_hi - r;
            int v = sSeq[t];
            const char* srow = (t == 2047) ? (const char*)zrow
                                           : (const char*)(ptab + (size_t)v * 128);
            GLL16(srow + sd * 16, (char*)sKb[s] + k * 1024);
        }
        const char* bsrc = SBg + ((size_t)b * 32 + ch) * 17408;
        #pragma unroll
        for (int kk = 0; kk < 2; ++kk) {
            int k = w * 2 + kk;
            GLL16(bsrc + k * 1024 + lane * 16, (char*)sBlob[s] + k * 1024);
        }
        if (w == 7)
            GLL4(bsrc + 16384 + lane * 4, (char*)sBlob[s] + 16384);
    };

    STAGE(0, 0); STAGE(1, 1);

    #pragma unroll 1
    for (int c = 0; c < 32; ++c) {
        const int cur = c & 1;
        if (c < 31) {
            if (w == 7) asm volatile("s_waitcnt vmcnt(5)" ::: "memory");
            else        asm volatile("s_waitcnt vmcnt(4)" ::: "memory");
        } else {
            asm volatile("s_waitcnt vmcnt(0)" ::: "memory");
        }
        __builtin_amdgcn_s_barrier();            // B0: all waves' DMA landed
        __builtin_amdgcn_sched_barrier(0);

        const unsigned short* kb = sKb[cur];
        const unsigned* wt = (const unsigned*)(sBlob[cur]);
        const float* dgv = (const float*)(sBlob[cur] + 16384);

        // phase Z partial: wave w covers d2 in [8w, 8w+8); lane = i
        float zp = 0.f;
        #pragma unroll
        for (int j = 0; j < 8; ++j) {
            int d2 = w * 8 + j;
            unsigned wp = wt[d2 * 64 + lane];    // conflict-free
            float ua = __shfl(u0, d2);
            float ub = __shfl(u1, d2);
            zp = fmaf(bf2f((unsigned short)(wp & 0xffff)), ua, zp);
            zp = fmaf(bf2f((unsigned short)(wp >> 16)),    ub, zp);
        }
        sPZ[w][lane] = zp;
        asm volatile("s_waitcnt lgkmcnt(0)" ::: "memory");
        __builtin_amdgcn_s_barrier();            // B1
        __builtin_amdgcn_sched_barrier(0);

        // redundant full reduce (identical order in every wave) -> z, ci
        float z = 0.f;
        #pragma unroll
        for (int ww = 0; ww < 8; ++ww) z += sPZ[ww][lane];
        float ci = z * dgv[lane];

        // phase C partial: wave w covers i in [8w, 8w+8); lane = d-pair
        float du0 = 0.f, du1 = 0.f;
        #pragma unroll
        for (int j = 0; j < 8; ++j) {
            int i = w * 8 + j;
            float zi  = __shfl(z, i);
            float cii = __shfl(ci, i);
            unsigned kp = *(const unsigned*)((const char*)kb + i * 256 + lane * 4);
            float k0 = bf2f((unsigned short)(kp & 0xffff));
            float k1 = bf2f((unsigned short)(kp >> 16));
            du0  = fmaf(zi,  k0, du0);  du1  = fmaf(zi,  k1, du1);
            csv0 = fmaf(cii, k0, csv0); csv1 = fmaf(cii, k1, csv1);
        }
        sPC[w][lane] = make_float2(du0, du1);
        asm volatile("s_waitcnt lgkmcnt(0)" ::: "memory");
        __builtin_amdgcn_s_barrier();            // B2: buf cur fully consumed
        __builtin_amdgcn_sched_barrier(0);

        if (c + 2 < 32) STAGE(cur, c + 2);       // overwrite is now safe

        float s0 = 0.f, s1 = 0.f;
        #pragma unroll
        for (int ww = 0; ww < 8; ++ww) {
            float2 p = sPC[ww][lane];
            s0 += p.x; s1 += p.y;
        }
        u0 -= s0; u1 -= s1;
    }

    // final csv reduce across waves
    asm volatile("s_waitcnt lgkmcnt(0)" ::: "memory");
    __builtin_amdgcn_s_barrier();                // all u-update reads done
    sPC[w][lane] = make_float2(csv0, csv1);
    asm volatile("s_waitcnt lgkmcnt(0)" ::: "memory");
    __builtin_amdgcn_s_barrier();
    if (w == 0) {
        float a0 = 0.f, a1 = 0.f;
        #pragma unroll
        for (int ww = 0; ww < 8; ++ww) {
            float2 p = sPC[ww][lane];
            a0 += p.x; a1 += p.y;
        }
        csb[b * 128 + lane * 2]     = a0;
        csb[b * 128 + lane * 2 + 1] = a1;
    }
}

// ---------------- out = cs @ Wo + bo : [64,128]@[128,32000] ----------------
__global__ __launch_bounds__(256) void out_kernel(
    const float* __restrict__ cs, const float* __restrict__ Wo,
    const float* __restrict__ bo, float* __restrict__ out)
{
    __shared__ float sC[64 * 128];
    const int tid = threadIdx.x;
    #pragma unroll
    for (int r = 0; r < 8; ++r)
        ((float4*)sC)[r * 256 + tid] = ((const float4*)cs)[r * 256 + tid];
    __syncthreads();

    const int j = blockIdx.x * 256 + tid;
    float acc[64];
    #pragma unroll
    for (int r = 0; r < 64; ++r) acc[r] = 0.f;
    for (int k0 = 0; k0 < 128; k0 += 4) {
        float w0 = Wo[(size_t)(k0 + 0) * Vv + j];
        float w1 = Wo[(size_t)(k0 + 1) * Vv + j];
        float w2 = Wo[(size_t)(k0 + 2) * Vv + j];
        float w3 = Wo[(size_t)(k0 + 3) * Vv + j];
        #pragma unroll
        for (int r = 0; r < 64; ++r) {
            float4 c = *(const float4*)&sC[r * 128 + k0];
            acc[r] = fmaf(c.x, w0, fmaf(c.y, w1, fmaf(c.z, w2, fmaf(c.w, w3, acc[r]))));
        }
    }
    float bj = bo[j];
    #pragma unroll
    for (int r = 0; r < 64; ++r)
        out[(size_t)r * Vv + j] = acc[r] + bj;
}

extern "C" void kernel_launch(void* const* d_in, const int* in_sizes, int n_in,
                              void* d_out, int out_size, void* d_ws, size_t ws_size,
                              hipStream_t stream)
{
    const int*   seq   = (const int*)  d_in[0];
    const float* embed = (const float*)d_in[1];
    const float* W1    = (const float*)d_in[2];
    const float* b1    = (const float*)d_in[3];
    const float* W2    = (const float*)d_in[4];
    const float* b2    = (const float*)d_in[5];
    const float* gamma = (const float*)d_in[6];
    const float* beta  = (const float*)d_in[7];
    const float* Wp    = (const float*)d_in[8];
    const float* bp    = (const float*)d_in[9];
    const float* Wo    = (const float*)d_in[10];
    const float* bo    = (const float*)d_in[11];
    float* out = (float*)d_out;

    char* wsb = (char*)d_ws;
    unsigned short* ptab = (unsigned short*)(wsb);                 //  8,192,000 B
    char*           SBg  = wsb + 8192000;                          // 35,651,584 B
    unsigned short* W1T  = (unsigned short*)(wsb + 43843584);      //    262,144 B
    unsigned short* W2T  = (unsigned short*)(wsb + 44105728);      //    262,144 B
    unsigned short* WpT  = (unsigned short*)(wsb + 44367872);      //     65,536 B
    float*          csb  = (float*)(wsb + 44433408);               //     32,768 B
    float*          zrow = (float*)(wsb + 44466176);               //        256 B

    prep_kernel<<<576, 256, 0, stream>>>(W1, W2, Wp, W1T, W2T, WpT, zrow);
    enc_kernel<<<Vv / 32, 512, 0, stream>>>(embed, W1T, b1, W2T, b2,
                                            gamma, beta, WpT, bp, ptab);
    sprep_kernel<<<2048, 256, 0, stream>>>(seq, ptab, SBg);
    scan_kernel<<<64, 512, 0, stream>>>(seq, ptab, SBg, zrow, csb);
    out_kernel<<<Vv / 256, 256, 0, stream>>>(csb, Wo, bo, out);
}

// Round 11
// 211.030 us; speedup vs baseline: 1.3332x; 1.1829x over previous
//
#include <hip/hip_runtime.h>

#define Vv 32000
#define Ll 2048

typedef __bf16 bf16x8 __attribute__((ext_vector_type(8)));
typedef float  f32x4  __attribute__((ext_vector_type(4)));

__device__ __forceinline__ unsigned short f2bf(float f) {
    unsigned u = __builtin_bit_cast(unsigned, f);
    u += 0x7fffu + ((u >> 16) & 1u);
    return (unsigned short)(u >> 16);
}
__device__ __forceinline__ float bf2f(unsigned short s) {
    unsigned u = (unsigned)s << 16;
    return __builtin_bit_cast(float, u);
}
__device__ __forceinline__ void unpk8(uint4 v, float* o) {
    o[0] = bf2f((unsigned short)(v.x & 0xffff)); o[1] = bf2f((unsigned short)(v.x >> 16));
    o[2] = bf2f((unsigned short)(v.y & 0xffff)); o[3] = bf2f((unsigned short)(v.y >> 16));
    o[4] = bf2f((unsigned short)(v.z & 0xffff)); o[5] = bf2f((unsigned short)(v.z >> 16));
    o[6] = bf2f((unsigned short)(v.w & 0xffff)); o[7] = bf2f((unsigned short)(v.w >> 16));
}

#define MFMA(a, b, c) __builtin_amdgcn_mfma_f32_16x16x32_bf16(a, b, c, 0, 0, 0)
#define GLL16(gsrc, ldst)                                                    \
    __builtin_amdgcn_global_load_lds(                                        \
        (const __attribute__((address_space(1))) void*)(gsrc),               \
        (__attribute__((address_space(3))) void*)(ldst), 16, 0, 0)
#define GLL4(gsrc, ldst)                                                     \
    __builtin_amdgcn_global_load_lds(                                        \
        (const __attribute__((address_space(1))) void*)(gsrc),               \
        (__attribute__((address_space(3))) void*)(ldst), 4, 0, 0)

// ---------------- prep: transpose W1/W2/Wp to bf16 [N][K]; zero pad row ----
__global__ __launch_bounds__(256) void prep_kernel(
    const float* __restrict__ W1, const float* __restrict__ W2,
    const float* __restrict__ Wp, unsigned short* __restrict__ W1T,
    unsigned short* __restrict__ W2T, unsigned short* __restrict__ WpT,
    float* __restrict__ zrow)
{
    int idx = blockIdx.x * 256 + threadIdx.x;   // pair index
    if (blockIdx.x == 575 && threadIdx.x < 64) zrow[threadIdx.x] = 0.f;
    if (idx < 65536) {                           // W1T [512][256] <- W1 [256][512]
        int e0 = idx * 2, n = e0 >> 8, k = e0 & 255;
        unsigned lo = f2bf(W1[(size_t)k * 512 + n]);
        unsigned hi = f2bf(W1[(size_t)(k + 1) * 512 + n]);
        ((unsigned*)W1T)[idx] = lo | (hi << 16);
    } else if (idx < 131072) {                   // W2T [256][512] <- W2 [512][256]
        int i = idx - 65536, e0 = i * 2, n = e0 >> 9, k = e0 & 511;
        unsigned lo = f2bf(W2[(size_t)k * 256 + n]);
        unsigned hi = f2bf(W2[(size_t)(k + 1) * 256 + n]);
        ((unsigned*)W2T)[i] = lo | (hi << 16);
    } else {                                     // WpT [128][256] <- Wp [256][128]
        int i = idx - 131072, e0 = i * 2, n = e0 >> 8, k = e0 & 255;
        unsigned lo = f2bf(Wp[(size_t)k * 128 + n]);
        unsigned hi = f2bf(Wp[(size_t)(k + 1) * 128 + n]);
        ((unsigned*)WpT)[i] = lo | (hi << 16);
    }
}

// ---------------- embconv: embed f32 -> bf16 table (same f2bf rounding) ----
__global__ __launch_bounds__(256) void embconv_kernel(
    const float* __restrict__ embed, unsigned short* __restrict__ embbf)
{
    int idx = blockIdx.x * 256 + threadIdx.x;    // 8-float group, 1,024,000 total
    const float4 a = ((const float4*)embed)[(size_t)idx * 2];
    const float4 b = ((const float4*)embed)[(size_t)idx * 2 + 1];
    uint4 pk;
    pk.x = (unsigned)f2bf(a.x) | ((unsigned)f2bf(a.y) << 16);
    pk.y = (unsigned)f2bf(a.z) | ((unsigned)f2bf(a.w) << 16);
    pk.z = (unsigned)f2bf(b.x) | ((unsigned)f2bf(b.y) << 16);
    pk.w = (unsigned)f2bf(b.z) | ((unsigned)f2bf(b.w) << 16);
    ((uint4*)embbf)[idx] = pk;
}

// ---------------- fused MFMA encoder v5: 32 vocab rows / block, grid 1000 --
// E tile staged by global_load_lds from the pre-converted bf16 embed table
// (per-lane pre-swizzled source, linear LDS dest). Rest as v4.
__global__ __launch_bounds__(512, 4) void enc_kernel(
    const unsigned short* __restrict__ embbf,
    const unsigned short* __restrict__ W1T, const float* __restrict__ b1,
    const unsigned short* __restrict__ W2T, const float* __restrict__ b2,
    const float* __restrict__ gamma, const float* __restrict__ beta,
    const unsigned short* __restrict__ WpT, const float* __restrict__ bp,
    unsigned short* __restrict__ ptab)
{
    __shared__ char sE[32 * 512];      // bf16 [32][256], swizzled (e, then h)
    __shared__ char sU[32 * 1024];     // bf16 [32][512], swizzled U; later p stage
    __shared__ float sPart[32][8][2];
    __shared__ float sMR[32][2];

    const int tid  = threadIdx.x;
    const int lane = tid & 63;
    const int w    = tid >> 6;         // 0..7 column-slice group
    const int l15  = lane & 15;
    const int lk   = lane >> 4;        // 0..3
    const int n0   = blockIdx.x * 32;
    const int swl  = (l15 & 7) << 4;   // A-frag row swizzle (row&7 == l15&7)

    // ---- E tile via async DMA: dest linear (wave-uniform base + lane*16),
    //      source pre-swizzled so sE[row][slot] = embbf_row[slot ^ swz] ----
    #pragma unroll
    for (int cc = 0; cc < 2; ++cc) {
        int c = cc * 512 + tid;          // 0..1023 16B-chunks
        int row  = c >> 5;
        int slot = (c & 31) << 4;
        int kbs  = slot ^ ((row & 7) << 4);
        GLL16((const char*)embbf + (size_t)(n0 + row) * 512 + kbs,
              sE + (cc * 512 + (tid & 448)) * 16);
    }
    __syncthreads();                                   // B1 (drains vmcnt)

    // ---- GEMM1: U = relu(E @ W1 + b1); wave cols [w*64, w*64+64), K=256 ----
    #pragma unroll
    for (int nf2 = 0; nf2 < 2; ++nf2) {
        f32x4 acc1[2][2];
        acc1[0][0] = acc1[0][1] = acc1[1][0] = acc1[1][1] = (f32x4){0.f, 0.f, 0.f, 0.f};
        const char* w1p = (const char*)W1T + (size_t)(w * 64 + nf2 * 32 + l15) * 512 + lk * 16;
        bf16x8 bfr[16];
        #pragma unroll
        for (int ks = 0; ks < 8; ++ks) {
            bfr[ks * 2]     = *(const bf16x8*)(w1p + ks * 64);
            bfr[ks * 2 + 1] = *(const bf16x8*)(w1p + 16 * 512 + ks * 64);
        }
        #pragma unroll
        for (int ks = 0; ks < 8; ++ks) {
            int ka = (ks * 64 + lk * 16) ^ swl;
            bf16x8 a0 = *(const bf16x8*)(sE + l15 * 512 + ka);
            bf16x8 a1 = *(const bf16x8*)(sE + (16 + l15) * 512 + ka);
            acc1[0][0] = MFMA(a0, bfr[ks * 2],     acc1[0][0]);
            acc1[1][0] = MFMA(a1, bfr[ks * 2],     acc1[1][0]);
            acc1[0][1] = MFMA(a0, bfr[ks * 2 + 1], acc1[0][1]);
            acc1[1][1] = MFMA(a1, bfr[ks * 2 + 1], acc1[1][1]);
        }
        float bv0 = b1[w * 64 + nf2 * 32 + l15];
        float bv1 = b1[w * 64 + nf2 * 32 + 16 + l15];
        #pragma unroll
        for (int mi = 0; mi < 2; ++mi)
            #pragma unroll
            for (int nj = 0; nj < 2; ++nj) {
                float bv = nj ? bv1 : bv0;
                #pragma unroll
                for (int r = 0; r < 4; ++r) {
                    int row = mi * 16 + lk * 4 + r;
                    int col = w * 64 + nf2 * 32 + nj * 16 + l15;
                    float v = fmaxf(acc1[mi][nj][r] + bv, 0.f);
                    *(unsigned short*)(sU + row * 1024 + ((col * 2) ^ ((row & 7) << 4))) = f2bf(v);
                }
            }
    }
    __syncthreads();                                   // B2

    // ---- GEMM2: F = U @ W2; wave cols [w*32, w*32+32), K=512, 2 halves ----
    f32x4 acc2[2][2];
    acc2[0][0] = acc2[0][1] = acc2[1][0] = acc2[1][1] = (f32x4){0.f, 0.f, 0.f, 0.f};
    {
        const char* w2p = (const char*)W2T + (size_t)(w * 32 + l15) * 1024 + lk * 16;
        #pragma unroll
        for (int h = 0; h < 2; ++h) {
            bf16x8 bfr[16];
            #pragma unroll
            for (int ks = 0; ks < 8; ++ks) {
                int kss = h * 8 + ks;
                bfr[ks * 2]     = *(const bf16x8*)(w2p + kss * 64);
                bfr[ks * 2 + 1] = *(const bf16x8*)(w2p + 16 * 1024 + kss * 64);
            }
            #pragma unroll
            for (int ks = 0; ks < 8; ++ks) {
                int kss = h * 8 + ks;
                int ka = (kss * 64 + lk * 16) ^ swl;
                bf16x8 a0 = *(const bf16x8*)(sU + l15 * 1024 + ka);
                bf16x8 a1 = *(const bf16x8*)(sU + (16 + l15) * 1024 + ka);
                acc2[0][0] = MFMA(a0, bfr[ks * 2],     acc2[0][0]);
                acc2[1][0] = MFMA(a1, bfr[ks * 2],     acc2[1][0]);
                acc2[0][1] = MFMA(a0, bfr[ks * 2 + 1], acc2[0][1]);
                acc2[1][1] = MFMA(a1, bfr[ks * 2 + 1], acc2[1][1]);
            }
        }
    }

    // ---- x = e + f + b2 ; LN partials (wave covers 32 cols) ----
    float b2v[2], gv[2], btv[2];
    #pragma unroll
    for (int nj = 0; nj < 2; ++nj) {
        int col = w * 32 + nj * 16 + l15;
        b2v[nj] = b2[col]; gv[nj] = gamma[col]; btv[nj] = beta[col];
    }
    #pragma unroll
    for (int mi = 0; mi < 2; ++mi)
        #pragma unroll
        for (int r = 0; r < 4; ++r) {
            int row = mi * 16 + lk * 4 + r;
            int swr = (row & 7) << 4;
            float s1 = 0.f, s2 = 0.f;
            #pragma unroll
            for (int nj = 0; nj < 2; ++nj) {
                int col = w * 32 + nj * 16 + l15;
                float e = bf2f(*(const unsigned short*)(sE + row * 512 + ((col * 2) ^ swr)));
                float x = acc2[mi][nj][r] + b2v[nj] + e;
                acc2[mi][nj][r] = x;
                s1 += x; s2 = fmaf(x, x, s2);
            }
            s1 += __shfl_xor(s1, 1); s2 += __shfl_xor(s2, 1);
            s1 += __shfl_xor(s1, 2); s2 += __shfl_xor(s2, 2);
            s1 += __shfl_xor(s1, 4); s2 += __shfl_xor(s2, 4);
            s1 += __shfl_xor(s1, 8); s2 += __shfl_xor(s2, 8);
            if (l15 == 0) { sPart[row][w][0] = s1; sPart[row][w][1] = s2; }
        }
    __syncthreads();                                   // B3
    if (tid < 32) {
        float t1 = 0.f, t2 = 0.f;
        #pragma unroll
        for (int ww = 0; ww < 8; ++ww) { t1 += sPart[tid][ww][0]; t2 += sPart[tid][ww][1]; }
        float mu  = t1 * (1.f / 256.f);
        float var = t2 * (1.f / 256.f) - mu * mu;
        sMR[tid][0] = mu;
        sMR[tid][1] = rsqrtf(var + 1e-5f);
    }
    __syncthreads();                                   // B4
    // ---- h -> sE (bf16, swizzled; overwrites e) ----
    #pragma unroll
    for (int mi = 0; mi < 2; ++mi)
        #pragma unroll
        for (int r = 0; r < 4; ++r) {
            int row = mi * 16 + lk * 4 + r;
            int swr = (row & 7) << 4;
            float mu = sMR[row][0], rs = sMR[row][1];
            #pragma unroll
            for (int nj = 0; nj < 2; ++nj) {
                int col = w * 32 + nj * 16 + l15;
                float h = (acc2[mi][nj][r] - mu) * rs * gv[nj] + btv[nj];
                *(unsigned short*)(sE + row * 512 + ((col * 2) ^ swr)) = f2bf(h);
            }
        }
    __syncthreads();                                   // B5

    // ---- GEMM3: p = h @ Wp + bp; wave cols [w*16, w*16+16), K=256 ----
    f32x4 acc3[2];
    acc3[0] = acc3[1] = (f32x4){0.f, 0.f, 0.f, 0.f};
    {
        const char* wpp = (const char*)WpT + (size_t)(w * 16 + l15) * 512 + lk * 16;
        bf16x8 bfr[8];
        #pragma unroll
        for (int ks = 0; ks < 8; ++ks)
            bfr[ks] = *(const bf16x8*)(wpp + ks * 64);
        #pragma unroll
        for (int ks = 0; ks < 8; ++ks) {
            int ka = (ks * 64 + lk * 16) ^ swl;
            bf16x8 a0 = *(const bf16x8*)(sE + l15 * 512 + ka);
            bf16x8 a1 = *(const bf16x8*)(sE + (16 + l15) * 512 + ka);
            acc3[0] = MFMA(a0, bfr[ks], acc3[0]);
            acc3[1] = MFMA(a1, bfr[ks], acc3[1]);
        }
    }
    {
        float bpv = bp[w * 16 + l15];
        #pragma unroll
        for (int mi = 0; mi < 2; ++mi)
            #pragma unroll
            for (int r = 0; r < 4; ++r) {
                int row = mi * 16 + lk * 4 + r;
                int col = w * 16 + l15;
                *(unsigned short*)(sU + row * 256 + col * 2) = f2bf(acc3[mi][r] + bpv);
            }
    }
    __syncthreads();                                   // B6
    {
        int row = tid >> 4, slot = (tid & 15) << 4;    // 512 chunks = 32x512B
        *(uint4*)((char*)ptab + (size_t)(n0 + row) * 256 + slot) =
            *(const uint4*)(sU + row * 256 + slot);
    }
}

// ---------------- sprep v4: 256 threads / chunk; Gram + W = (D+L)^-1 K ----
__global__ __launch_bounds__(256) void sprep_kernel(
    const int* __restrict__ seq, const unsigned short* __restrict__ ptab,
    char* __restrict__ SBg)
{
    __shared__ unsigned short sK[64 * 136];   // 17408 B, rows 272 B
    __shared__ float sG[10 * 16 * 17];        // 10880 B, block-major [q][r][c]
    __shared__ float sM[4 * 16 * 17];         //  4352 B
    __shared__ float sQ[64];                  //   256 B
    __shared__ float sW[64 * 132];            // 33792 B, rows 528 B

    const int blk  = blockIdx.x;              // 0..2047
    const int b    = blk >> 5, ch = blk & 31;
    const int t_hi = 2047 - (ch << 6);
    const int tid  = threadIdx.x;
    const int lane = tid & 63;
    const int wv   = tid >> 6;                // 0..3
    const int l15  = lane & 15, lk = lane >> 4;

    // ---- stage K rows: 1024 16B-chunks over 256 threads ----
    #pragma unroll
    for (int i = 0; i < 4; ++i) {
        int c = i * 256 + tid;
        int row = c >> 4, j = c & 15;
        int t = t_hi - row;
        if (t == 2047) {
            *(uint4*)((char*)sK + row * 272 + j * 16) = (uint4){0u, 0u, 0u, 0u};
        } else {
            int v = seq[b * 2048 + t];
            *(uint4*)((char*)sK + row * 272 + j * 16) =
                *(const uint4*)((const char*)(ptab + (size_t)v * 128) + j * 16);
        }
    }
    __syncthreads();

    // ---- Gram lower blocks via MFMA, tiles distributed across 4 waves ----
    {
        int q = 0;
        #pragma unroll
        for (int ti = 0; ti < 4; ++ti)
            #pragma unroll
            for (int tj = 0; tj <= ti; ++tj, ++q) {
                if ((q & 3) != wv) continue;           // wave-uniform branch
                f32x4 acc = (f32x4){0.f, 0.f, 0.f, 0.f};
                #pragma unroll
                for (int ks = 0; ks < 4; ++ks) {
                    bf16x8 fa = *(const bf16x8*)((const char*)sK + (ti * 16 + l15) * 272 + ks * 64 + lk * 16);
                    bf16x8 fb = *(const bf16x8*)((const char*)sK + (tj * 16 + l15) * 272 + ks * 64 + lk * 16);
                    acc = MFMA(fa, fb, acc);
                }
                #pragma unroll
                for (int r = 0; r < 4; ++r)
                    sG[q * 272 + (lk * 4 + r) * 17 + l15] = acc[r];
            }
    }
    __syncthreads();

    // ---- reciprocals of diagonal ----
    if (tid < 64) {
        int dq = (lk * (lk + 3)) >> 1;
        float d = sG[dq * 272 + l15 * 17 + l15] + 1e-6f;
        sQ[tid] = 1.0f / d;
    }
    __syncthreads();

    // ---- invert 4 diagonal blocks (tid<64: g = lk, column c = l15) ----
    if (tid < 64) {
        const int g = lk, c = l15;
        const float* Tg = &sG[((g * (g + 3)) >> 1) * 272];
        float qv[16], av[16], mcol[16];
        #pragma unroll
        for (int r = 0; r < 16; ++r) { qv[r] = sQ[g * 16 + r]; av[r] = 0.f; }
        #pragma unroll
        for (int r = 0; r < 16; ++r) {
            float mr = (((r == c) ? 1.f : 0.f) - av[r]) * qv[r];
            mcol[r] = mr;
            #pragma unroll
            for (int i = r + 1; i < 16; ++i)
                av[i] = fmaf(Tg[i * 17 + r], mr, av[i]);
        }
        #pragma unroll
        for (int r = 0; r < 16; ++r)
            sM[g * 272 + r * 17 + c] = mcol[r];
    }
    __syncthreads();

    // ---- W build: thread = (rr = tid&15 row-in-block, dq8 = tid>>4: 8 cols) ----
    const int rr = tid & 15, dq8 = tid >> 4;
    #pragma unroll 1
    for (int s = 0; s < 4; ++s) {
        float a[8];
        {   // init from K row 16s+rr, cols [dq8*8, +8)
            uint4 kv = *(const uint4*)((const char*)sK + (16 * s + rr) * 272 + dq8 * 16);
            unpk8(kv, a);
        }
        #pragma unroll
        for (int j = 0; j < 3; ++j) {           // subtract T_sj @ W_j, j < s
            if (j >= s) break;
            const float* Tb = &sG[(((s * (s + 1)) >> 1) + j) * 272];
            #pragma unroll
            for (int m = 0; m < 16; ++m) {
                float t = Tb[rr * 17 + m];
                const float* wrow = &sW[(16 * j + m) * 132 + dq8 * 8];
                f32x4 w0 = *(const f32x4*)(wrow);
                f32x4 w1 = *(const f32x4*)(wrow + 4);
                a[0] = fmaf(-t, w0.x, a[0]); a[1] = fmaf(-t, w0.y, a[1]);
                a[2] = fmaf(-t, w0.z, a[2]); a[3] = fmaf(-t, w0.w, a[3]);
                a[4] = fmaf(-t, w1.x, a[4]); a[5] = fmaf(-t, w1.y, a[5]);
                a[6] = fmaf(-t, w1.z, a[6]); a[7] = fmaf(-t, w1.w, a[7]);
            }
        }
        {   // write tmp rows of block s
            float* wrow = &sW[(16 * s + rr) * 132 + dq8 * 8];
            *(f32x4*)(wrow)     = (f32x4){a[0], a[1], a[2], a[3]};
            *(f32x4*)(wrow + 4) = (f32x4){a[4], a[5], a[6], a[7]};
        }
        __syncthreads();
        float o[8];
        #pragma unroll
        for (int v = 0; v < 8; ++v) o[v] = 0.f;
        #pragma unroll
        for (int cc = 0; cc < 16; ++cc) {       // W_s = M_s @ tmp
            float mm = sM[s * 272 + rr * 17 + cc];
            const float* wrow = &sW[(16 * s + cc) * 132 + dq8 * 8];
            f32x4 w0 = *(const f32x4*)(wrow);
            f32x4 w1 = *(const f32x4*)(wrow + 4);
            o[0] = fmaf(mm, w0.x, o[0]); o[1] = fmaf(mm, w0.y, o[1]);
            o[2] = fmaf(mm, w0.z, o[2]); o[3] = fmaf(mm, w0.w, o[3]);
            o[4] = fmaf(mm, w1.x, o[4]); o[5] = fmaf(mm, w1.y, o[5]);
            o[6] = fmaf(mm, w1.z, o[6]); o[7] = fmaf(mm, w1.w, o[7]);
        }
        __syncthreads();                        // all tmp reads done
        {   // overwrite block-s rows with final W_s
            float* wrow = &sW[(16 * s + rr) * 132 + dq8 * 8];
            *(f32x4*)(wrow)     = (f32x4){o[0], o[1], o[2], o[3]};
            *(f32x4*)(wrow + 4) = (f32x4){o[4], o[5], o[6], o[7]};
        }
        __syncthreads();
    }

    // ---- write WTP (transposed, packed bf16) + diag ----
    char* blob = SBg + (size_t)blk * 17408;
    unsigned* wtp = (unsigned*)blob;
    {
        int i = tid & 63;
        #pragma unroll
        for (int dg = 0; dg < 16; ++dg) {
            int d2 = (tid >> 6) * 16 + dg;
            float2 wvp = *(const float2*)&sW[i * 132 + d2 * 2];
            wtp[d2 * 64 + i] = (unsigned)f2bf(wvp.x) | ((unsigned)f2bf(wvp.y) << 16);
        }
    }
    if (tid < 64) {
        int dq = (lk * (lk + 3)) >> 1;
        float d = sG[dq * 272 + l15 * 17 + l15] + 1e-6f;
        *(float*)(blob + 16384 + tid * 4) = d;
    }
}

// ---------------- serial chunked scan v2: 8-wave cooperative chunk body ----
__global__ __launch_bounds__(512) void scan_kernel(
    const int* __restrict__ seq, const unsigned short* __restrict__ ptab,
    const char* __restrict__ SBg, const float* __restrict__ zrow,
    float* __restrict__ csb)
{
    __shared__ int sSeq[2048];
    __shared__ unsigned short sKb[2][8192];      // [64][128] bf16, linear
    __shared__ __align__(16) char sBlob[2][16640]; // WTP 16K + diag 256B
    __shared__ float  sPZ[8][64];                // per-wave z partials
    __shared__ float2 sPC[8][64];                // per-wave du partials / csv

    const int b    = blockIdx.x;
    const int tid  = threadIdx.x;
    const int lane = tid & 63;
    const int w    = tid >> 6;

    *(int4*)&sSeq[tid * 4] = *(const int4*)&seq[b * 2048 + tid * 4];
    float u0, u1;                                // u pair (2*lane, 2*lane+1)
    {
        int vq = seq[b * 2048 + 2047];
        unsigned pk = *(const unsigned*)(ptab + (size_t)vq * 128 + lane * 2);
        u0 = bf2f((unsigned short)(pk & 0xffff));
        u1 = bf2f((unsigned short)(pk >> 16));
    }
    float csv0 = 0.f, csv1 = 0.f;
    __syncthreads();            // once: sSeq visible (drains vmcnt, harmless here)

    auto STAGE = [&](int s, int ch) {            // 4 GLLs/wave (wave 7: 5)
        int t_hi = 2047 - (ch << 6);
        #pragma unroll
        for (int kk = 0; kk < 2; ++kk) {
            int k = w * 2 + kk;
            int g = k * 64 + lane;
            int r = g >> 4, sd = g & 15;
            int t = t_hi - r;
            int v = sSeq[t];
            const char* srow = (t == 2047) ? (const char*)zrow
                                           : (const char*)(ptab + (size_t)v * 128);
            GLL16(srow + sd * 16, (char*)sKb[s] + k * 1024);
        }
        const char* bsrc = SBg + ((size_t)b * 32 + ch) * 17408;
        #pragma unroll
        for (int kk = 0; kk < 2; ++kk) {
            int k = w * 2 + kk;
            GLL16(bsrc + k * 1024 + lane * 16, (char*)sBlob[s] + k * 1024);
        }
        if (w == 7)
            GLL4(bsrc + 16384 + lane * 4, (char*)sBlob[s] + 16384);
    };

    STAGE(0, 0); STAGE(1, 1);

    #pragma unroll 1
    for (int c = 0; c < 32; ++c) {
        const int cur = c & 1;
        if (c < 31) {
            if (w == 7) asm volatile("s_waitcnt vmcnt(5)" ::: "memory");
            else        asm volatile("s_waitcnt vmcnt(4)" ::: "memory");
        } else {
            asm volatile("s_waitcnt vmcnt(0)" ::: "memory");
        }
        __builtin_amdgcn_s_barrier();            // B0: all waves' DMA landed
        __builtin_amdgcn_sched_barrier(0);

        const unsigned short* kb = sKb[cur];
        const unsigned* wt = (const unsigned*)(sBlob[cur]);
        const float* dgv = (const float*)(sBlob[cur] + 16384);

        // phase Z partial: wave w covers d2 in [8w, 8w+8); lane = i
        float zp = 0.f;
        #pragma unroll
        for (int j = 0; j < 8; ++j) {
            int d2 = w * 8 + j;
            unsigned wp = wt[d2 * 64 + lane];    // conflict-free
            float ua = __shfl(u0, d2);
            float ub = __shfl(u1, d2);
            zp = fmaf(bf2f((unsigned short)(wp & 0xffff)), ua, zp);
            zp = fmaf(bf2f((unsigned short)(wp >> 16)),    ub, zp);
        }
        sPZ[w][lane] = zp;
        asm volatile("s_waitcnt lgkmcnt(0)" ::: "memory");
        __builtin_amdgcn_s_barrier();            // B1
        __builtin_amdgcn_sched_barrier(0);

        // redundant full reduce (identical order in every wave) -> z, ci
        float z = 0.f;
        #pragma unroll
        for (int ww = 0; ww < 8; ++ww) z += sPZ[ww][lane];
        float ci = z * dgv[lane];

        // phase C partial: wave w covers i in [8w, 8w+8); lane = d-pair
        float du0 = 0.f, du1 = 0.f;
        #pragma unroll
        for (int j = 0; j < 8; ++j) {
            int i = w * 8 + j;
            float zi  = __shfl(z, i);
            float cii = __shfl(ci, i);
            unsigned kp = *(const unsigned*)((const char*)kb + i * 256 + lane * 4);
            float k0 = bf2f((unsigned short)(kp & 0xffff));
            float k1 = bf2f((unsigned short)(kp >> 16));
            du0  = fmaf(zi,  k0, du0);  du1  = fmaf(zi,  k1, du1);
            csv0 = fmaf(cii, k0, csv0); csv1 = fmaf(cii, k1, csv1);
        }
        sPC[w][lane] = make_float2(du0, du1);
        asm volatile("s_waitcnt lgkmcnt(0)" ::: "memory");
        __builtin_amdgcn_s_barrier();            // B2: buf cur fully consumed
        __builtin_amdgcn_sched_barrier(0);

        if (c + 2 < 32) STAGE(cur, c + 2);       // overwrite is now safe

        float s0 = 0.f, s1 = 0.f;
        #pragma unroll
        for (int ww = 0; ww < 8; ++ww) {
            float2 p = sPC[ww][lane];
            s0 += p.x; s1 += p.y;
        }
        u0 -= s0; u1 -= s1;
    }

    // final csv reduce across waves
    asm volatile("s_waitcnt lgkmcnt(0)" ::: "memory");
    __builtin_amdgcn_s_barrier();                // all u-update reads done
    sPC[w][lane] = make_float2(csv0, csv1);
    asm volatile("s_waitcnt lgkmcnt(0)" ::: "memory");
    __builtin_amdgcn_s_barrier();
    if (w == 0) {
        float a0 = 0.f, a1 = 0.f;
        #pragma unroll
        for (int ww = 0; ww < 8; ++ww) {
            float2 p = sPC[ww][lane];
            a0 += p.x; a1 += p.y;
        }
        csb[b * 128 + lane * 2]     = a0;
        csb[b * 128 + lane * 2 + 1] = a1;
    }
}

// ---------------- out v2: 500 blocks; block = 64 cols x 4 row-groups ------
__global__ __launch_bounds__(256) void out_kernel(
    const float* __restrict__ cs, const float* __restrict__ Wo,
    const float* __restrict__ bo, float* __restrict__ out)
{
    __shared__ float sC[64 * 128];
    const int tid = threadIdx.x;
    #pragma unroll
    for (int r = 0; r < 8; ++r)
        ((float4*)sC)[r * 256 + tid] = ((const float4*)cs)[r * 256 + tid];
    __syncthreads();

    const int j  = blockIdx.x * 64 + (tid & 63);   // vocab col
    const int rg = tid >> 6;                       // 0..3 -> rows rg*16..+16
    float acc[16];
    #pragma unroll
    for (int r = 0; r < 16; ++r) acc[r] = 0.f;
    for (int k0 = 0; k0 < 128; k0 += 4) {
        float w0 = Wo[(size_t)(k0 + 0) * Vv + j];
        float w1 = Wo[(size_t)(k0 + 1) * Vv + j];
        float w2 = Wo[(size_t)(k0 + 2) * Vv + j];
        float w3 = Wo[(size_t)(k0 + 3) * Vv + j];
        #pragma unroll
        for (int r = 0; r < 16; ++r) {
            float4 c = *(const float4*)&sC[(rg * 16 + r) * 128 + k0];
            acc[r] = fmaf(c.x, w0, fmaf(c.y, w1, fmaf(c.z, w2, fmaf(c.w, w3, acc[r]))));
        }
    }
    float bj = bo[j];
    #pragma unroll
    for (int r = 0; r < 16; ++r)
        out[(size_t)(rg * 16 + r) * Vv + j] = acc[r] + bj;
}

extern "C" void kernel_launch(void* const* d_in, const int* in_sizes, int n_in,
                              void* d_out, int out_size, void* d_ws, size_t ws_size,
                              hipStream_t stream)
{
    const int*   seq   = (const int*)  d_in[0];
    const float* embed = (const float*)d_in[1];
    const float* W1    = (const float*)d_in[2];
    const float* b1    = (const float*)d_in[3];
    const float* W2    = (const float*)d_in[4];
    const float* b2    = (const float*)d_in[5];
    const float* gamma = (const float*)d_in[6];
    const float* beta  = (const float*)d_in[7];
    const float* Wp    = (const float*)d_in[8];
    const float* bp    = (const float*)d_in[9];
    const float* Wo    = (const float*)d_in[10];
    const float* bo    = (const float*)d_in[11];
    float* out = (float*)d_out;

    char* wsb = (char*)d_ws;
    unsigned short* ptab  = (unsigned short*)(wsb);                //  8,192,000 B
    char*           SBg   = wsb + 8192000;                         // 35,651,584 B
    unsigned short* W1T   = (unsigned short*)(wsb + 43843584);     //    262,144 B
    unsigned short* W2T   = (unsigned short*)(wsb + 44105728);     //    262,144 B
    unsigned short* WpT   = (unsigned short*)(wsb + 44367872);     //     65,536 B
    float*          csb   = (float*)(wsb + 44433408);              //     32,768 B
    float*          zrow  = (float*)(wsb + 44466176);              //        256 B
    unsigned short* embbf = (unsigned short*)(wsb + 44466432);     // 16,384,000 B

    prep_kernel<<<576, 256, 0, stream>>>(W1, W2, Wp, W1T, W2T, WpT, zrow);
    embconv_kernel<<<4000, 256, 0, stream>>>(embed, embbf);
    enc_kernel<<<Vv / 32, 512, 0, stream>>>(embbf, W1T, b1, W2T, b2,
                                            gamma, beta, WpT, bp, ptab);
    sprep_kernel<<<2048, 256, 0, stream>>>(seq, ptab, SBg);
    scan_kernel<<<64, 512, 0, stream>>>(seq, ptab, SBg, zrow, csb);
    out_kernel<<<Vv / 64, 256, 0, stream>>>(csb, Wo, bo, out);
}

// Round 12
// 205.783 us; speedup vs baseline: 1.3672x; 1.0255x over previous
//
#include <hip/hip_runtime.h>

#define Vv 32000
#define Ll 2048

typedef __bf16 bf16x8 __attribute__((ext_vector_type(8)));
typedef float  f32x4  __attribute__((ext_vector_type(4)));

__device__ __forceinline__ unsigned short f2bf(float f) {
    unsigned u = __builtin_bit_cast(unsigned, f);
    u += 0x7fffu + ((u >> 16) & 1u);
    return (unsigned short)(u >> 16);
}
__device__ __forceinline__ float bf2f(unsigned short s) {
    unsigned u = (unsigned)s << 16;
    return __builtin_bit_cast(float, u);
}
__device__ __forceinline__ void unpk8(uint4 v, float* o) {
    o[0] = bf2f((unsigned short)(v.x & 0xffff)); o[1] = bf2f((unsigned short)(v.x >> 16));
    o[2] = bf2f((unsigned short)(v.y & 0xffff)); o[3] = bf2f((unsigned short)(v.y >> 16));
    o[4] = bf2f((unsigned short)(v.z & 0xffff)); o[5] = bf2f((unsigned short)(v.z >> 16));
    o[6] = bf2f((unsigned short)(v.w & 0xffff)); o[7] = bf2f((unsigned short)(v.w >> 16));
}

#define MFMA(a, b, c) __builtin_amdgcn_mfma_f32_16x16x32_bf16(a, b, c, 0, 0, 0)
#define GLL16(gsrc, ldst)                                                    \
    __builtin_amdgcn_global_load_lds(                                        \
        (const __attribute__((address_space(1))) void*)(gsrc),               \
        (__attribute__((address_space(3))) void*)(ldst), 16, 0, 0)
#define GLL4(gsrc, ldst)                                                     \
    __builtin_amdgcn_global_load_lds(                                        \
        (const __attribute__((address_space(1))) void*)(gsrc),               \
        (__attribute__((address_space(3))) void*)(ldst), 4, 0, 0)

// ---------------- prep: transpose W1/W2/Wp to bf16 [N][K]; zero pad row ----
__global__ __launch_bounds__(256) void prep_kernel(
    const float* __restrict__ W1, const float* __restrict__ W2,
    const float* __restrict__ Wp, unsigned short* __restrict__ W1T,
    unsigned short* __restrict__ W2T, unsigned short* __restrict__ WpT,
    float* __restrict__ zrow)
{
    int idx = blockIdx.x * 256 + threadIdx.x;   // pair index
    if (blockIdx.x == 575 && threadIdx.x < 64) zrow[threadIdx.x] = 0.f;
    if (idx < 65536) {                           // W1T [512][256] <- W1 [256][512]
        int e0 = idx * 2, n = e0 >> 8, k = e0 & 255;
        unsigned lo = f2bf(W1[(size_t)k * 512 + n]);
        unsigned hi = f2bf(W1[(size_t)(k + 1) * 512 + n]);
        ((unsigned*)W1T)[idx] = lo | (hi << 16);
    } else if (idx < 131072) {                   // W2T [256][512] <- W2 [512][256]
        int i = idx - 65536, e0 = i * 2, n = e0 >> 9, k = e0 & 511;
        unsigned lo = f2bf(W2[(size_t)k * 256 + n]);
        unsigned hi = f2bf(W2[(size_t)(k + 1) * 256 + n]);
        ((unsigned*)W2T)[i] = lo | (hi << 16);
    } else {                                     // WpT [128][256] <- Wp [256][128]
        int i = idx - 131072, e0 = i * 2, n = e0 >> 8, k = e0 & 255;
        unsigned lo = f2bf(Wp[(size_t)k * 128 + n]);
        unsigned hi = f2bf(Wp[(size_t)(k + 1) * 128 + n]);
        ((unsigned*)WpT)[i] = lo | (hi << 16);
    }
}

// ---------------- embconv: embed f32 -> bf16 table (same f2bf rounding) ----
__global__ __launch_bounds__(256) void embconv_kernel(
    const float* __restrict__ embed, unsigned short* __restrict__ embbf)
{
    int idx = blockIdx.x * 256 + threadIdx.x;    // 8-float group, 1,024,000 total
    const float4 a = ((const float4*)embed)[(size_t)idx * 2];
    const float4 b = ((const float4*)embed)[(size_t)idx * 2 + 1];
    uint4 pk;
    pk.x = (unsigned)f2bf(a.x) | ((unsigned)f2bf(a.y) << 16);
    pk.y = (unsigned)f2bf(a.z) | ((unsigned)f2bf(a.w) << 16);
    pk.z = (unsigned)f2bf(b.x) | ((unsigned)f2bf(b.y) << 16);
    pk.w = (unsigned)f2bf(b.z) | ((unsigned)f2bf(b.w) << 16);
    ((uint4*)embbf)[idx] = pk;
}

// ---------------- encA: U = relu(E @ W1 + b1), tiled 128x128, DMA-staged ---
// grid = 250 row-tiles x 4 col-tiles = 1000, 512 threads (8 waves = 2x4).
__global__ __launch_bounds__(512, 2) void encA_kernel(
    const unsigned short* __restrict__ embbf,
    const unsigned short* __restrict__ W1T, const float* __restrict__ b1,
    unsigned short* __restrict__ Ug)
{
    __shared__ char sA[65536];         // [128 rows][256K] bf16, swizzled
    __shared__ char sB[65536];         // [128 cols][256K] bf16, swizzled

    const int tid  = threadIdx.x;
    const int lane = tid & 63;
    const int w    = tid >> 6;
    const int rh   = w >> 2;           // 0..1 row half
    const int cq   = w & 3;            // 0..3 col quarter
    const int l15  = lane & 15;
    const int lk   = lane >> 4;
    const int n0   = (blockIdx.x >> 2) * 128;
    const int c0   = (blockIdx.x & 3) * 128;
    const int swl  = (l15 & 7) << 4;

    // ---- DMA A and B tiles (pre-swizzled source, linear dest) ----
    #pragma unroll
    for (int i = 0; i < 8; ++i) {
        int id = i * 512 + tid;
        int row = id >> 5, slot = (id & 31) << 4;
        GLL16((const char*)embbf + (size_t)(n0 + row) * 512 + (slot ^ ((row & 7) << 4)),
              sA + (size_t)(i * 512 + (tid & 448)) * 16);
    }
    #pragma unroll
    for (int i = 0; i < 8; ++i) {
        int id = i * 512 + tid;
        int col = id >> 5, slot = (id & 31) << 4;
        GLL16((const char*)W1T + (size_t)(c0 + col) * 512 + (slot ^ ((col & 7) << 4)),
              sB + (size_t)(i * 512 + (tid & 448)) * 16);
    }
    __syncthreads();

    // ---- GEMM: wave = 64 rows x 32 cols, K=256 ----
    f32x4 acc[4][2];
    #pragma unroll
    for (int m = 0; m < 4; ++m)
        #pragma unroll
        for (int n = 0; n < 2; ++n) acc[m][n] = (f32x4){0.f, 0.f, 0.f, 0.f};
    #pragma unroll
    for (int ks = 0; ks < 8; ++ks) {
        int ka = (ks * 64 + lk * 16) ^ swl;
        bf16x8 b0 = *(const bf16x8*)(sB + (cq * 32 + l15) * 512 + ka);
        bf16x8 b1v = *(const bf16x8*)(sB + (cq * 32 + 16 + l15) * 512 + ka);
        #pragma unroll
        for (int mi = 0; mi < 4; ++mi) {
            bf16x8 a = *(const bf16x8*)(sA + (rh * 64 + mi * 16 + l15) * 512 + ka);
            acc[mi][0] = MFMA(a, b0,  acc[mi][0]);
            acc[mi][1] = MFMA(a, b1v, acc[mi][1]);
        }
    }

    // ---- epilogue: relu+bias, bf16, stage to sA, coalesced store ----
    float bv0 = b1[c0 + cq * 32 + l15];
    float bv1 = b1[c0 + cq * 32 + 16 + l15];
    __syncthreads();                   // all A/B reads done, reuse sA
    #pragma unroll
    for (int mi = 0; mi < 4; ++mi)
        #pragma unroll
        for (int nj = 0; nj < 2; ++nj) {
            float bv = nj ? bv1 : bv0;
            #pragma unroll
            for (int r = 0; r < 4; ++r) {
                int row = rh * 64 + mi * 16 + lk * 4 + r;
                int col = cq * 32 + nj * 16 + l15;
                *(unsigned short*)(sA + row * 256 + col * 2) =
                    f2bf(fmaxf(acc[mi][nj][r] + bv, 0.f));
            }
        }
    __syncthreads();
    #pragma unroll
    for (int i = 0; i < 4; ++i) {
        int id = i * 512 + tid;
        int row = id >> 4, slot = (id & 15) << 4;
        *(uint4*)((char*)Ug + (size_t)(n0 + row) * 1024 + c0 * 2 + slot) =
            *(const uint4*)(sA + row * 256 + slot);
    }
}

// ---------------- encB: h = LN(e + U@W2 + b2); p = h@Wp + bp -> ptab -------
// 32 rows/block, grid 1000, 512 threads = 8 waves x 32 cols.
// W2 streamed as 8x32KB chunks, double-buffered (vmcnt(4) + s_barrier).
__global__ __launch_bounds__(512, 2) void encB_kernel(
    const unsigned short* __restrict__ embbf, const unsigned short* __restrict__ Ug,
    const char* __restrict__ W2Tc, const float* __restrict__ b2,
    const float* __restrict__ gamma, const float* __restrict__ beta,
    const unsigned short* __restrict__ WpT, const float* __restrict__ bp,
    unsigned short* __restrict__ ptab)
{
    __shared__ char sE[32 * 512];      // 16KB: e (then h), swizzled 512B rows
    __shared__ char sU[32 * 1024];     // 32KB: U tile, swizzled 1024B rows; later p
    __shared__ char sWB[65536];        // 2x32KB W2 chunks / 64KB Wp
    __shared__ float sPart[32][8][2];
    __shared__ float sMR[32][2];

    const int tid  = threadIdx.x;
    const int lane = tid & 63;
    const int w    = tid >> 6;
    const int l15  = lane & 15;
    const int lk   = lane >> 4;
    const int n0   = blockIdx.x * 32;
    const int swl  = (l15 & 7) << 4;

    // ---- prologue DMA: E (2/thr), U (4/thr), W2 chunks 0,1 (4/thr each) ----
    #pragma unroll
    for (int i = 0; i < 2; ++i) {
        int id = i * 512 + tid;
        int row = id >> 5, slot = (id & 31) << 4;
        GLL16((const char*)embbf + (size_t)(n0 + row) * 512 + (slot ^ ((row & 7) << 4)),
              sE + (size_t)(i * 512 + (tid & 448)) * 16);
    }
    #pragma unroll
    for (int i = 0; i < 4; ++i) {
        int id = i * 512 + tid;
        int row = id >> 6, slot = (id & 63) << 4;
        GLL16((const char*)Ug + (size_t)(n0 + row) * 1024 + (slot ^ ((row & 7) << 4)),
              sU + (size_t)(i * 512 + (tid & 448)) * 16);
    }
    auto STAGE_W = [&](int s, int kc) {      // 4 GLL16 / thread
        #pragma unroll
        for (int i = 0; i < 4; ++i) {
            int id = i * 512 + tid;
            int col = id >> 3, j = id & 7;
            GLL16(W2Tc + (size_t)col * 1024 + kc * 128 + ((j * 16) ^ ((col & 7) << 4)),
                  sWB + s * 32768 + (size_t)(i * 512 + (tid & 448)) * 16);
        }
    };
    STAGE_W(0, 0); STAGE_W(1, 1);
    __syncthreads();                          // drain all prologue DMA

    // ---- GEMM2: K=512 in 8 chunks of 64; acc order = k ascending ----
    f32x4 acc2[2][2];
    acc2[0][0] = acc2[0][1] = acc2[1][0] = acc2[1][1] = (f32x4){0.f, 0.f, 0.f, 0.f};
    #pragma unroll 1
    for (int c = 0; c < 8; ++c) {
        const int cur = c & 1;
        if (c >= 2) {
            if (c < 7) { asm volatile("s_waitcnt vmcnt(4)" ::: "memory"); }
            else       { asm volatile("s_waitcnt vmcnt(0)" ::: "memory"); }
        }
        __builtin_amdgcn_s_barrier();
        __builtin_amdgcn_sched_barrier(0);

        const char* wb = sWB + cur * 32768;
        #pragma unroll
        for (int ks2 = 0; ks2 < 2; ++ks2) {
            int kwb = (ks2 * 64 + lk * 16) ^ swl;
            int kau = (c * 128 + ks2 * 64 + lk * 16) ^ swl;
            bf16x8 b0  = *(const bf16x8*)(wb + (w * 32 + l15) * 128 + kwb);
            bf16x8 b1v = *(const bf16x8*)(wb + (w * 32 + 16 + l15) * 128 + kwb);
            bf16x8 a0  = *(const bf16x8*)(sU + l15 * 1024 + kau);
            bf16x8 a1  = *(const bf16x8*)(sU + (16 + l15) * 1024 + kau);
            acc2[0][0] = MFMA(a0, b0,  acc2[0][0]);
            acc2[1][0] = MFMA(a1, b0,  acc2[1][0]);
            acc2[0][1] = MFMA(a0, b1v, acc2[0][1]);
            acc2[1][1] = MFMA(a1, b1v, acc2[1][1]);
        }
        asm volatile("s_waitcnt lgkmcnt(0)" ::: "memory");
        __builtin_amdgcn_s_barrier();
        __builtin_amdgcn_sched_barrier(0);
        if (c + 2 < 8) STAGE_W(cur, c + 2);
    }

    // ---- stage Wp (full 64KB into sWB); lands during LN ----
    #pragma unroll
    for (int i = 0; i < 8; ++i) {
        int id = i * 512 + tid;
        int col = id >> 5, slot = (id & 31) << 4;
        GLL16((const char*)WpT + (size_t)col * 512 + (slot ^ ((col & 7) << 4)),
              sWB + (size_t)(i * 512 + (tid & 448)) * 16);
    }

    // ---- x = e + f + b2 ; LN partials (identical to v5) ----
    float b2v[2], gv[2], btv[2];
    #pragma unroll
    for (int nj = 0; nj < 2; ++nj) {
        int col = w * 32 + nj * 16 + l15;
        b2v[nj] = b2[col]; gv[nj] = gamma[col]; btv[nj] = beta[col];
    }
    #pragma unroll
    for (int mi = 0; mi < 2; ++mi)
        #pragma unroll
        for (int r = 0; r < 4; ++r) {
            int row = mi * 16 + lk * 4 + r;
            int swr = (row & 7) << 4;
            float s1 = 0.f, s2 = 0.f;
            #pragma unroll
            for (int nj = 0; nj < 2; ++nj) {
                int col = w * 32 + nj * 16 + l15;
                float e = bf2f(*(const unsigned short*)(sE + row * 512 + ((col * 2) ^ swr)));
                float x = acc2[mi][nj][r] + b2v[nj] + e;
                acc2[mi][nj][r] = x;
                s1 += x; s2 = fmaf(x, x, s2);
            }
            s1 += __shfl_xor(s1, 1); s2 += __shfl_xor(s2, 1);
            s1 += __shfl_xor(s1, 2); s2 += __shfl_xor(s2, 2);
            s1 += __shfl_xor(s1, 4); s2 += __shfl_xor(s2, 4);
            s1 += __shfl_xor(s1, 8); s2 += __shfl_xor(s2, 8);
            if (l15 == 0) { sPart[row][w][0] = s1; sPart[row][w][1] = s2; }
        }
    __syncthreads();                       // drains Wp DMA too
    if (tid < 32) {
        float t1 = 0.f, t2 = 0.f;
        #pragma unroll
        for (int ww = 0; ww < 8; ++ww) { t1 += sPart[tid][ww][0]; t2 += sPart[tid][ww][1]; }
        float mu  = t1 * (1.f / 256.f);
        float var = t2 * (1.f / 256.f) - mu * mu;
        sMR[tid][0] = mu;
        sMR[tid][1] = rsqrtf(var + 1e-5f);
    }
    __syncthreads();
    // ---- h -> sE (bf16, swizzled; overwrites e) ----
    #pragma unroll
    for (int mi = 0; mi < 2; ++mi)
        #pragma unroll
        for (int r = 0; r < 4; ++r) {
            int row = mi * 16 + lk * 4 + r;
            int swr = (row & 7) << 4;
            float mu = sMR[row][0], rs = sMR[row][1];
            #pragma unroll
            for (int nj = 0; nj < 2; ++nj) {
                int col = w * 32 + nj * 16 + l15;
                float h = (acc2[mi][nj][r] - mu) * rs * gv[nj] + btv[nj];
                *(unsigned short*)(sE + row * 512 + ((col * 2) ^ swr)) = f2bf(h);
            }
        }
    __syncthreads();

    // ---- GEMM3: p = h @ Wp + bp; wave cols [w*16,+16), K=256, Wp in LDS ----
    f32x4 acc3[2];
    acc3[0] = acc3[1] = (f32x4){0.f, 0.f, 0.f, 0.f};
    #pragma unroll
    for (int ks = 0; ks < 8; ++ks) {
        int ka = (ks * 64 + lk * 16) ^ swl;
        bf16x8 b0 = *(const bf16x8*)(sWB + (w * 16 + l15) * 512 + ka);
        bf16x8 a0 = *(const bf16x8*)(sE + l15 * 512 + ka);
        bf16x8 a1 = *(const bf16x8*)(sE + (16 + l15) * 512 + ka);
        acc3[0] = MFMA(a0, b0, acc3[0]);
        acc3[1] = MFMA(a1, b0, acc3[1]);
    }
    {
        float bpv = bp[w * 16 + l15];
        #pragma unroll
        for (int mi = 0; mi < 2; ++mi)
            #pragma unroll
            for (int r = 0; r < 4; ++r) {
                int row = mi * 16 + lk * 4 + r;
                int col = w * 16 + l15;
                *(unsigned short*)(sU + row * 256 + col * 2) = f2bf(acc3[mi][r] + bpv);
            }
    }
    __syncthreads();
    {
        int row = tid >> 4, slot = (tid & 15) << 4;
        *(uint4*)((char*)ptab + (size_t)(n0 + row) * 256 + slot) =
            *(const uint4*)(sU + row * 256 + slot);
    }
}

// ---------------- sprep v4: 256 threads / chunk; Gram + W = (D+L)^-1 K ----
__global__ __launch_bounds__(256) void sprep_kernel(
    const int* __restrict__ seq, const unsigned short* __restrict__ ptab,
    char* __restrict__ SBg)
{
    __shared__ unsigned short sK[64 * 136];   // 17408 B, rows 272 B
    __shared__ float sG[10 * 16 * 17];        // 10880 B, block-major [q][r][c]
    __shared__ float sM[4 * 16 * 17];         //  4352 B
    __shared__ float sQ[64];                  //   256 B
    __shared__ float sW[64 * 132];            // 33792 B, rows 528 B

    const int blk  = blockIdx.x;              // 0..2047
    const int b    = blk >> 5, ch = blk & 31;
    const int t_hi = 2047 - (ch << 6);
    const int tid  = threadIdx.x;
    const int lane = tid & 63;
    const int wv   = tid >> 6;                // 0..3
    const int l15  = lane & 15, lk = lane >> 4;

    // ---- stage K rows: 1024 16B-chunks over 256 threads ----
    #pragma unroll
    for (int i = 0; i < 4; ++i) {
        int c = i * 256 + tid;
        int row = c >> 4, j = c & 15;
        int t = t_hi - row;
        if (t == 2047) {
            *(uint4*)((char*)sK + row * 272 + j * 16) = (uint4){0u, 0u, 0u, 0u};
        } else {
            int v = seq[b * 2048 + t];
            *(uint4*)((char*)sK + row * 272 + j * 16) =
                *(const uint4*)((const char*)(ptab + (size_t)v * 128) + j * 16);
        }
    }
    __syncthreads();

    // ---- Gram lower blocks via MFMA, tiles distributed across 4 waves ----
    {
        int q = 0;
        #pragma unroll
        for (int ti = 0; ti < 4; ++ti)
            #pragma unroll
            for (int tj = 0; tj <= ti; ++tj, ++q) {
                if ((q & 3) != wv) continue;           // wave-uniform branch
                f32x4 acc = (f32x4){0.f, 0.f, 0.f, 0.f};
                #pragma unroll
                for (int ks = 0; ks < 4; ++ks) {
                    bf16x8 fa = *(const bf16x8*)((const char*)sK + (ti * 16 + l15) * 272 + ks * 64 + lk * 16);
                    bf16x8 fb = *(const bf16x8*)((const char*)sK + (tj * 16 + l15) * 272 + ks * 64 + lk * 16);
                    acc = MFMA(fa, fb, acc);
                }
                #pragma unroll
                for (int r = 0; r < 4; ++r)
                    sG[q * 272 + (lk * 4 + r) * 17 + l15] = acc[r];
            }
    }
    __syncthreads();

    // ---- reciprocals of diagonal ----
    if (tid < 64) {
        int dq = (lk * (lk + 3)) >> 1;
        float d = sG[dq * 272 + l15 * 17 + l15] + 1e-6f;
        sQ[tid] = 1.0f / d;
    }
    __syncthreads();

    // ---- invert 4 diagonal blocks (tid<64: g = lk, column c = l15) ----
    if (tid < 64) {
        const int g = lk, c = l15;
        const float* Tg = &sG[((g * (g + 3)) >> 1) * 272];
        float qv[16], av[16], mcol[16];
        #pragma unroll
        for (int r = 0; r < 16; ++r) { qv[r] = sQ[g * 16 + r]; av[r] = 0.f; }
        #pragma unroll
        for (int r = 0; r < 16; ++r) {
            float mr = (((r == c) ? 1.f : 0.f) - av[r]) * qv[r];
            mcol[r] = mr;
            #pragma unroll
            for (int i = r + 1; i < 16; ++i)
                av[i] = fmaf(Tg[i * 17 + r], mr, av[i]);
        }
        #pragma unroll
        for (int r = 0; r < 16; ++r)
            sM[g * 272 + r * 17 + c] = mcol[r];
    }
    __syncthreads();

    // ---- W build: thread = (rr = tid&15 row-in-block, dq8 = tid>>4: 8 cols) ----
    const int rr = tid & 15, dq8 = tid >> 4;
    #pragma unroll 1
    for (int s = 0; s < 4; ++s) {
        float a[8];
        {   // init from K row 16s+rr, cols [dq8*8, +8)
            uint4 kv = *(const uint4*)((const char*)sK + (16 * s + rr) * 272 + dq8 * 16);
            unpk8(kv, a);
        }
        #pragma unroll
        for (int j = 0; j < 3; ++j) {           // subtract T_sj @ W_j, j < s
            if (j >= s) break;
            const float* Tb = &sG[(((s * (s + 1)) >> 1) + j) * 272];
            #pragma unroll
            for (int m = 0; m < 16; ++m) {
                float t = Tb[rr * 17 + m];
                const float* wrow = &sW[(16 * j + m) * 132 + dq8 * 8];
                f32x4 w0 = *(const f32x4*)(wrow);
                f32x4 w1 = *(const f32x4*)(wrow + 4);
                a[0] = fmaf(-t, w0.x, a[0]); a[1] = fmaf(-t, w0.y, a[1]);
                a[2] = fmaf(-t, w0.z, a[2]); a[3] = fmaf(-t, w0.w, a[3]);
                a[4] = fmaf(-t, w1.x, a[4]); a[5] = fmaf(-t, w1.y, a[5]);
                a[6] = fmaf(-t, w1.z, a[6]); a[7] = fmaf(-t, w1.w, a[7]);
            }
        }
        {   // write tmp rows of block s
            float* wrow = &sW[(16 * s + rr) * 132 + dq8 * 8];
            *(f32x4*)(wrow)     = (f32x4){a[0], a[1], a[2], a[3]};
            *(f32x4*)(wrow + 4) = (f32x4){a[4], a[5], a[6], a[7]};
        }
        __syncthreads();
        float o[8];
        #pragma unroll
        for (int v = 0; v < 8; ++v) o[v] = 0.f;
        #pragma unroll
        for (int cc = 0; cc < 16; ++cc) {       // W_s = M_s @ tmp
            float mm = sM[s * 272 + rr * 17 + cc];
            const float* wrow = &sW[(16 * s + cc) * 132 + dq8 * 8];
            f32x4 w0 = *(const f32x4*)(wrow);
            f32x4 w1 = *(const f32x4*)(wrow + 4);
            o[0] = fmaf(mm, w0.x, o[0]); o[1] = fmaf(mm, w0.y, o[1]);
            o[2] = fmaf(mm, w0.z, o[2]); o[3] = fmaf(mm, w0.w, o[3]);
            o[4] = fmaf(mm, w1.x, o[4]); o[5] = fmaf(mm, w1.y, o[5]);
            o[6] = fmaf(mm, w1.z, o[6]); o[7] = fmaf(mm, w1.w, o[7]);
        }
        __syncthreads();                        // all tmp reads done
        {   // overwrite block-s rows with final W_s
            float* wrow = &sW[(16 * s + rr) * 132 + dq8 * 8];
            *(f32x4*)(wrow)     = (f32x4){o[0], o[1], o[2], o[3]};
            *(f32x4*)(wrow + 4) = (f32x4){o[4], o[5], o[6], o[7]};
        }
        __syncthreads();
    }

    // ---- write WTP (transposed, packed bf16) + diag ----
    char* blob = SBg + (size_t)blk * 17408;
    unsigned* wtp = (unsigned*)blob;
    {
        int i = tid & 63;
        #pragma unroll
        for (int dg = 0; dg < 16; ++dg) {
            int d2 = (tid >> 6) * 16 + dg;
            float2 wvp = *(const float2*)&sW[i * 132 + d2 * 2];
            wtp[d2 * 64 + i] = (unsigned)f2bf(wvp.x) | ((unsigned)f2bf(wvp.y) << 16);
        }
    }
    if (tid < 64) {
        int dq = (lk * (lk + 3)) >> 1;
        float d = sG[dq * 272 + l15 * 17 + l15] + 1e-6f;
        *(float*)(blob + 16384 + tid * 4) = d;
    }
}

// ---------------- serial chunked scan v2: 8-wave cooperative chunk body ----
__global__ __launch_bounds__(512) void scan_kernel(
    const int* __restrict__ seq, const unsigned short* __restrict__ ptab,
    const char* __restrict__ SBg, const float* __restrict__ zrow,
    float* __restrict__ csb)
{
    __shared__ int sSeq[2048];
    __shared__ unsigned short sKb[2][8192];      // [64][128] bf16, linear
    __shared__ __align__(16) char sBlob[2][16640]; // WTP 16K + diag 256B
    __shared__ float  sPZ[8][64];                // per-wave z partials
    __shared__ float2 sPC[8][64];                // per-wave du partials / csv

    const int b    = blockIdx.x;
    const int tid  = threadIdx.x;
    const int lane = tid & 63;
    const int w    = tid >> 6;

    *(int4*)&sSeq[tid * 4] = *(const int4*)&seq[b * 2048 + tid * 4];
    float u0, u1;                                // u pair (2*lane, 2*lane+1)
    {
        int vq = seq[b * 2048 + 2047];
        unsigned pk = *(const unsigned*)(ptab + (size_t)vq * 128 + lane * 2);
        u0 = bf2f((unsigned short)(pk & 0xffff));
        u1 = bf2f((unsigned short)(pk >> 16));
    }
    float csv0 = 0.f, csv1 = 0.f;
    __syncthreads();            // once: sSeq visible (drains vmcnt, harmless here)

    auto STAGE = [&](int s, int ch) {            // 4 GLLs/wave (wave 7: 5)
        int t_hi = 2047 - (ch << 6);
        #pragma unroll
        for (int kk = 0; kk < 2; ++kk) {
            int k = w * 2 + kk;
            int g = k * 64 + lane;
            int r = g >> 4, sd = g & 15;
            int t = t_hi - r;
            int v = sSeq[t];
            const char* srow = (t == 2047) ? (const char*)zrow
                                           : (const char*)(ptab + (size_t)v * 128);
            GLL16(srow + sd * 16, (char*)sKb[s] + k * 1024);
        }
        const char* bsrc = SBg + ((size_t)b * 32 + ch) * 17408;
        #pragma unroll
        for (int kk = 0; kk < 2; ++kk) {
            int k = w * 2 + kk;
            GLL16(bsrc + k * 1024 + lane * 16, (char*)sBlob[s] + k * 1024);
        }
        if (w == 7)
            GLL4(bsrc + 16384 + lane * 4, (char*)sBlob[s] + 16384);
    };

    STAGE(0, 0); STAGE(1, 1);

    #pragma unroll 1
    for (int c = 0; c < 32; ++c) {
        const int cur = c & 1;
        if (c < 31) {
            if (w == 7) asm volatile("s_waitcnt vmcnt(5)" ::: "memory");
            else        asm volatile("s_waitcnt vmcnt(4)" ::: "memory");
        } else {
            asm volatile("s_waitcnt vmcnt(0)" ::: "memory");
        }
        __builtin_amdgcn_s_barrier();            // B0: all waves' DMA landed
        __builtin_amdgcn_sched_barrier(0);

        const unsigned short* kb = sKb[cur];
        const unsigned* wt = (const unsigned*)(sBlob[cur]);
        const float* dgv = (const float*)(sBlob[cur] + 16384);

        // phase Z partial: wave w covers d2 in [8w, 8w+8); lane = i
        float zp = 0.f;
        #pragma unroll
        for (int j = 0; j < 8; ++j) {
            int d2 = w * 8 + j;
            unsigned wp = wt[d2 * 64 + lane];    // conflict-free
            float ua = __shfl(u0, d2);
            float ub = __shfl(u1, d2);
            zp = fmaf(bf2f((unsigned short)(wp & 0xffff)), ua, zp);
            zp = fmaf(bf2f((unsigned short)(wp >> 16)),    ub, zp);
        }
        sPZ[w][lane] = zp;
        asm volatile("s_waitcnt lgkmcnt(0)" ::: "memory");
        __builtin_amdgcn_s_barrier();            // B1
        __builtin_amdgcn_sched_barrier(0);

        // redundant full reduce (identical order in every wave) -> z, ci
        float z = 0.f;
        #pragma unroll
        for (int ww = 0; ww < 8; ++ww) z += sPZ[ww][lane];
        float ci = z * dgv[lane];

        // phase C partial: wave w covers i in [8w, 8w+8); lane = d-pair
        float du0 = 0.f, du1 = 0.f;
        #pragma unroll
        for (int j = 0; j < 8; ++j) {
            int i = w * 8 + j;
            float zi  = __shfl(z, i);
            float cii = __shfl(ci, i);
            unsigned kp = *(const unsigned*)((const char*)kb + i * 256 + lane * 4);
            float k0 = bf2f((unsigned short)(kp & 0xffff));
            float k1 = bf2f((unsigned short)(kp >> 16));
            du0  = fmaf(zi,  k0, du0);  du1  = fmaf(zi,  k1, du1);
            csv0 = fmaf(cii, k0, csv0); csv1 = fmaf(cii, k1, csv1);
        }
        sPC[w][lane] = make_float2(du0, du1);
        asm volatile("s_waitcnt lgkmcnt(0)" ::: "memory");
        __builtin_amdgcn_s_barrier();            // B2: buf cur fully consumed
        __builtin_amdgcn_sched_barrier(0);

        if (c + 2 < 32) STAGE(cur, c + 2);       // overwrite is now safe

        float s0 = 0.f, s1 = 0.f;
        #pragma unroll
        for (int ww = 0; ww < 8; ++ww) {
            float2 p = sPC[ww][lane];
            s0 += p.x; s1 += p.y;
        }
        u0 -= s0; u1 -= s1;
    }

    // final csv reduce across waves
    asm volatile("s_waitcnt lgkmcnt(0)" ::: "memory");
    __builtin_amdgcn_s_barrier();                // all u-update reads done
    sPC[w][lane] = make_float2(csv0, csv1);
    asm volatile("s_waitcnt lgkmcnt(0)" ::: "memory");
    __builtin_amdgcn_s_barrier();
    if (w == 0) {
        float a0 = 0.f, a1 = 0.f;
        #pragma unroll
        for (int ww = 0; ww < 8; ++ww) {
            float2 p = sPC[ww][lane];
            a0 += p.x; a1 += p.y;
        }
        csb[b * 128 + lane * 2]     = a0;
        csb[b * 128 + lane * 2 + 1] = a1;
    }
}

// ---------------- out v2: 500 blocks; block = 64 cols x 4 row-groups ------
__global__ __launch_bounds__(256) void out_kernel(
    const float* __restrict__ cs, const float* __restrict__ Wo,
    const float* __restrict__ bo, float* __restrict__ out)
{
    __shared__ float sC[64 * 128];
    const int tid = threadIdx.x;
    #pragma unroll
    for (int r = 0; r < 8; ++r)
        ((float4*)sC)[r * 256 + tid] = ((const float4*)cs)[r * 256 + tid];
    __syncthreads();

    const int j  = blockIdx.x * 64 + (tid & 63);   // vocab col
    const int rg = tid >> 6;                       // 0..3 -> rows rg*16..+16
    float acc[16];
    #pragma unroll
    for (int r = 0; r < 16; ++r) acc[r] = 0.f;
    for (int k0 = 0; k0 < 128; k0 += 4) {
        float w0 = Wo[(size_t)(k0 + 0) * Vv + j];
        float w1 = Wo[(size_t)(k0 + 1) * Vv + j];
        float w2 = Wo[(size_t)(k0 + 2) * Vv + j];
        float w3 = Wo[(size_t)(k0 + 3) * Vv + j];
        #pragma unroll
        for (int r = 0; r < 16; ++r) {
            float4 c = *(const float4*)&sC[(rg * 16 + r) * 128 + k0];
            acc[r] = fmaf(c.x, w0, fmaf(c.y, w1, fmaf(c.z, w2, fmaf(c.w, w3, acc[r]))));
        }
    }
    float bj = bo[j];
    #pragma unroll
    for (int r = 0; r < 16; ++r)
        out[(size_t)(rg * 16 + r) * Vv + j] = acc[r] + bj;
}

extern "C" void kernel_launch(void* const* d_in, const int* in_sizes, int n_in,
                              void* d_out, int out_size, void* d_ws, size_t ws_size,
                              hipStream_t stream)
{
    const int*   seq   = (const int*)  d_in[0];
    const float* embed = (const float*)d_in[1];
    const float* W1    = (const float*)d_in[2];
    const float* b1    = (const float*)d_in[3];
    const float* W2    = (const float*)d_in[4];
    const float* b2    = (const float*)d_in[5];
    const float* gamma = (const float*)d_in[6];
    const float* beta  = (const float*)d_in[7];
    const float* Wp    = (const float*)d_in[8];
    const float* bp    = (const float*)d_in[9];
    const float* Wo    = (const float*)d_in[10];
    const float* bo    = (const float*)d_in[11];
    float* out = (float*)d_out;

    // ws layout: ptab | BIG (SBg  OVERLAPS  embbf+U; serial stream makes it safe:
    // embbf/U are dead before sprep writes SBg) | weight tables | csb | zrow
    char* wsb = (char*)d_ws;
    unsigned short* ptab  = (unsigned short*)(wsb);                //  8,192,000 B
    char*           SBg   = wsb + 8192000;                         // 35,651,584 B (region 49,152,000)
    unsigned short* embbf = (unsigned short*)(wsb + 8192000);      // 16,384,000 B (aliases SBg)
    unsigned short* Ug    = (unsigned short*)(wsb + 24576000);     // 32,768,000 B (aliases SBg)
    unsigned short* W1T   = (unsigned short*)(wsb + 57344000);     //    262,144 B
    unsigned short* W2T   = (unsigned short*)(wsb + 57606144);     //    262,144 B
    unsigned short* WpT   = (unsigned short*)(wsb + 57868288);     //     65,536 B
    float*          csb   = (float*)(wsb + 57933824);              //     32,768 B
    float*          zrow  = (float*)(wsb + 57966592);              //        256 B

    prep_kernel<<<576, 256, 0, stream>>>(W1, W2, Wp, W1T, W2T, WpT, zrow);
    embconv_kernel<<<4000, 256, 0, stream>>>(embed, embbf);
    encA_kernel<<<1000, 512, 0, stream>>>(embbf, W1T, b1, Ug);
    encB_kernel<<<1000, 512, 0, stream>>>(embbf, Ug, (const char*)W2T, b2,
                                          gamma, beta, WpT, bp, ptab);
    sprep_kernel<<<2048, 256, 0, stream>>>(seq, ptab, SBg);
    scan_kernel<<<64, 512, 0, stream>>>(seq, ptab, SBg, zrow, csb);
    out_kernel<<<Vv / 64, 256, 0, stream>>>(csb, Wo, bo, out);
}

// Round 13
// 205.144 us; speedup vs baseline: 1.3714x; 1.0031x over previous
//
#include <hip/hip_runtime.h>

#define Vv 32000
#define Ll 2048

typedef __bf16 bf16x8 __attribute__((ext_vector_type(8)));
typedef float  f32x4  __attribute__((ext_vector_type(4)));

__device__ __forceinline__ unsigned short f2bf(float f) {
    unsigned u = __builtin_bit_cast(unsigned, f);
    u += 0x7fffu + ((u >> 16) & 1u);
    return (unsigned short)(u >> 16);
}
__device__ __forceinline__ float bf2f(unsigned short s) {
    unsigned u = (unsigned)s << 16;
    return __builtin_bit_cast(float, u);
}
__device__ __forceinline__ void unpk8(uint4 v, float* o) {
    o[0] = bf2f((unsigned short)(v.x & 0xffff)); o[1] = bf2f((unsigned short)(v.x >> 16));
    o[2] = bf2f((unsigned short)(v.y & 0xffff)); o[3] = bf2f((unsigned short)(v.y >> 16));
    o[4] = bf2f((unsigned short)(v.z & 0xffff)); o[5] = bf2f((unsigned short)(v.z >> 16));
    o[6] = bf2f((unsigned short)(v.w & 0xffff)); o[7] = bf2f((unsigned short)(v.w >> 16));
}

#define MFMA(a, b, c) __builtin_amdgcn_mfma_f32_16x16x32_bf16(a, b, c, 0, 0, 0)
#define GLL16(gsrc, ldst)                                                    \
    __builtin_amdgcn_global_load_lds(                                        \
        (const __attribute__((address_space(1))) void*)(gsrc),               \
        (__attribute__((address_space(3))) void*)(ldst), 16, 0, 0)
#define GLL4(gsrc, ldst)                                                     \
    __builtin_amdgcn_global_load_lds(                                        \
        (const __attribute__((address_space(1))) void*)(gsrc),               \
        (__attribute__((address_space(3))) void*)(ldst), 4, 0, 0)

// ---------------- prep: transpose W1/W2/Wp to bf16 [N][K]; zero pad row ----
__global__ __launch_bounds__(256) void prep_kernel(
    const float* __restrict__ W1, const float* __restrict__ W2,
    const float* __restrict__ Wp, unsigned short* __restrict__ W1T,
    unsigned short* __restrict__ W2T, unsigned short* __restrict__ WpT,
    float* __restrict__ zrow)
{
    int idx = blockIdx.x * 256 + threadIdx.x;   // pair index
    if (blockIdx.x == 575 && threadIdx.x < 64) zrow[threadIdx.x] = 0.f;
    if (idx < 65536) {                           // W1T [512][256] <- W1 [256][512]
        int e0 = idx * 2, n = e0 >> 8, k = e0 & 255;
        unsigned lo = f2bf(W1[(size_t)k * 512 + n]);
        unsigned hi = f2bf(W1[(size_t)(k + 1) * 512 + n]);
        ((unsigned*)W1T)[idx] = lo | (hi << 16);
    } else if (idx < 131072) {                   // W2T [256][512] <- W2 [512][256]
        int i = idx - 65536, e0 = i * 2, n = e0 >> 9, k = e0 & 511;
        unsigned lo = f2bf(W2[(size_t)k * 256 + n]);
        unsigned hi = f2bf(W2[(size_t)(k + 1) * 256 + n]);
        ((unsigned*)W2T)[i] = lo | (hi << 16);
    } else {                                     // WpT [128][256] <- Wp [256][128]
        int i = idx - 131072, e0 = i * 2, n = e0 >> 8, k = e0 & 255;
        unsigned lo = f2bf(Wp[(size_t)k * 128 + n]);
        unsigned hi = f2bf(Wp[(size_t)(k + 1) * 128 + n]);
        ((unsigned*)WpT)[i] = lo | (hi << 16);
    }
}

// ---------------- embconv: embed f32 -> bf16 table (same f2bf rounding) ----
__global__ __launch_bounds__(256) void embconv_kernel(
    const float* __restrict__ embed, unsigned short* __restrict__ embbf)
{
    int idx = blockIdx.x * 256 + threadIdx.x;    // 8-float group, 1,024,000 total
    const float4 a = ((const float4*)embed)[(size_t)idx * 2];
    const float4 b = ((const float4*)embed)[(size_t)idx * 2 + 1];
    uint4 pk;
    pk.x = (unsigned)f2bf(a.x) | ((unsigned)f2bf(a.y) << 16);
    pk.y = (unsigned)f2bf(a.z) | ((unsigned)f2bf(a.w) << 16);
    pk.z = (unsigned)f2bf(b.x) | ((unsigned)f2bf(b.y) << 16);
    pk.w = (unsigned)f2bf(b.z) | ((unsigned)f2bf(b.w) << 16);
    ((uint4*)embbf)[idx] = pk;
}

// ---------------- encA: U = relu(E @ W1 + b1), tiled 128x128, DMA-staged ---
// grid = 250 row-tiles x 4 col-tiles = 1000, 512 threads (8 waves = 2x4).
__global__ __launch_bounds__(512, 2) void encA_kernel(
    const unsigned short* __restrict__ embbf,
    const unsigned short* __restrict__ W1T, const float* __restrict__ b1,
    unsigned short* __restrict__ Ug)
{
    __shared__ char sA[65536];         // [128 rows][256K] bf16, swizzled
    __shared__ char sB[65536];         // [128 cols][256K] bf16, swizzled

    const int tid  = threadIdx.x;
    const int lane = tid & 63;
    const int w    = tid >> 6;
    const int rh   = w >> 2;           // 0..1 row half
    const int cq   = w & 3;            // 0..3 col quarter
    const int l15  = lane & 15;
    const int lk   = lane >> 4;
    const int n0   = (blockIdx.x >> 2) * 128;
    const int c0   = (blockIdx.x & 3) * 128;
    const int swl  = (l15 & 7) << 4;

    // ---- DMA A and B tiles (pre-swizzled source, linear dest) ----
    #pragma unroll
    for (int i = 0; i < 8; ++i) {
        int id = i * 512 + tid;
        int row = id >> 5, slot = (id & 31) << 4;
        GLL16((const char*)embbf + (size_t)(n0 + row) * 512 + (slot ^ ((row & 7) << 4)),
              sA + (size_t)(i * 512 + (tid & 448)) * 16);
    }
    #pragma unroll
    for (int i = 0; i < 8; ++i) {
        int id = i * 512 + tid;
        int col = id >> 5, slot = (id & 31) << 4;
        GLL16((const char*)W1T + (size_t)(c0 + col) * 512 + (slot ^ ((col & 7) << 4)),
              sB + (size_t)(i * 512 + (tid & 448)) * 16);
    }
    __syncthreads();

    // ---- GEMM: wave = 64 rows x 32 cols, K=256 ----
    f32x4 acc[4][2];
    #pragma unroll
    for (int m = 0; m < 4; ++m)
        #pragma unroll
        for (int n = 0; n < 2; ++n) acc[m][n] = (f32x4){0.f, 0.f, 0.f, 0.f};
    #pragma unroll
    for (int ks = 0; ks < 8; ++ks) {
        int ka = (ks * 64 + lk * 16) ^ swl;
        bf16x8 b0 = *(const bf16x8*)(sB + (cq * 32 + l15) * 512 + ka);
        bf16x8 b1v = *(const bf16x8*)(sB + (cq * 32 + 16 + l15) * 512 + ka);
        #pragma unroll
        for (int mi = 0; mi < 4; ++mi) {
            bf16x8 a = *(const bf16x8*)(sA + (rh * 64 + mi * 16 + l15) * 512 + ka);
            acc[mi][0] = MFMA(a, b0,  acc[mi][0]);
            acc[mi][1] = MFMA(a, b1v, acc[mi][1]);
        }
    }

    // ---- epilogue: relu+bias, bf16, stage to sA, coalesced store ----
    float bv0 = b1[c0 + cq * 32 + l15];
    float bv1 = b1[c0 + cq * 32 + 16 + l15];
    __syncthreads();                   // all A/B reads done, reuse sA
    #pragma unroll
    for (int mi = 0; mi < 4; ++mi)
        #pragma unroll
        for (int nj = 0; nj < 2; ++nj) {
            float bv = nj ? bv1 : bv0;
            #pragma unroll
            for (int r = 0; r < 4; ++r) {
                int row = rh * 64 + mi * 16 + lk * 4 + r;
                int col = cq * 32 + nj * 16 + l15;
                *(unsigned short*)(sA + row * 256 + col * 2) =
                    f2bf(fmaxf(acc[mi][nj][r] + bv, 0.f));
            }
        }
    __syncthreads();
    #pragma unroll
    for (int i = 0; i < 4; ++i) {
        int id = i * 512 + tid;
        int row = id >> 4, slot = (id & 15) << 4;
        *(uint4*)((char*)Ug + (size_t)(n0 + row) * 1024 + c0 * 2 + slot) =
            *(const uint4*)(sA + row * 256 + slot);
    }
}

// ---------------- encB: h = LN(e + U@W2 + b2); p = h@Wp + bp -> ptab -------
// 32 rows/block, grid 1000, 512 threads = 8 waves x 32 cols.
// W2 streamed as 8x32KB chunks, double-buffered (vmcnt(4) + s_barrier).
__global__ __launch_bounds__(512, 2) void encB_kernel(
    const unsigned short* __restrict__ embbf, const unsigned short* __restrict__ Ug,
    const char* __restrict__ W2Tc, const float* __restrict__ b2,
    const float* __restrict__ gamma, const float* __restrict__ beta,
    const unsigned short* __restrict__ WpT, const float* __restrict__ bp,
    unsigned short* __restrict__ ptab)
{
    __shared__ char sE[32 * 512];      // 16KB: e (then h), swizzled 512B rows
    __shared__ char sU[32 * 1024];     // 32KB: U tile, swizzled 1024B rows; later p
    __shared__ char sWB[65536];        // 2x32KB W2 chunks / 64KB Wp
    __shared__ float sPart[32][8][2];
    __shared__ float sMR[32][2];

    const int tid  = threadIdx.x;
    const int lane = tid & 63;
    const int w    = tid >> 6;
    const int l15  = lane & 15;
    const int lk   = lane >> 4;
    const int n0   = blockIdx.x * 32;
    const int swl  = (l15 & 7) << 4;

    // ---- prologue DMA: E (2/thr), U (4/thr), W2 chunks 0,1 (4/thr each) ----
    #pragma unroll
    for (int i = 0; i < 2; ++i) {
        int id = i * 512 + tid;
        int row = id >> 5, slot = (id & 31) << 4;
        GLL16((const char*)embbf + (size_t)(n0 + row) * 512 + (slot ^ ((row & 7) << 4)),
              sE + (size_t)(i * 512 + (tid & 448)) * 16);
    }
    #pragma unroll
    for (int i = 0; i < 4; ++i) {
        int id = i * 512 + tid;
        int row = id >> 6, slot = (id & 63) << 4;
        GLL16((const char*)Ug + (size_t)(n0 + row) * 1024 + (slot ^ ((row & 7) << 4)),
              sU + (size_t)(i * 512 + (tid & 448)) * 16);
    }
    auto STAGE_W = [&](int s, int kc) {      // 4 GLL16 / thread
        #pragma unroll
        for (int i = 0; i < 4; ++i) {
            int id = i * 512 + tid;
            int col = id >> 3, j = id & 7;
            GLL16(W2Tc + (size_t)col * 1024 + kc * 128 + ((j * 16) ^ ((col & 7) << 4)),
                  sWB + s * 32768 + (size_t)(i * 512 + (tid & 448)) * 16);
        }
    };
    STAGE_W(0, 0); STAGE_W(1, 1);
    __syncthreads();                          // drain all prologue DMA

    // ---- GEMM2: K=512 in 8 chunks of 64; acc order = k ascending ----
    f32x4 acc2[2][2];
    acc2[0][0] = acc2[0][1] = acc2[1][0] = acc2[1][1] = (f32x4){0.f, 0.f, 0.f, 0.f};
    #pragma unroll 1
    for (int c = 0; c < 8; ++c) {
        const int cur = c & 1;
        if (c >= 2) {
            if (c < 7) { asm volatile("s_waitcnt vmcnt(4)" ::: "memory"); }
            else       { asm volatile("s_waitcnt vmcnt(0)" ::: "memory"); }
        }
        __builtin_amdgcn_s_barrier();
        __builtin_amdgcn_sched_barrier(0);

        const char* wb = sWB + cur * 32768;
        #pragma unroll
        for (int ks2 = 0; ks2 < 2; ++ks2) {
            int kwb = (ks2 * 64 + lk * 16) ^ swl;
            int kau = (c * 128 + ks2 * 64 + lk * 16) ^ swl;
            bf16x8 b0  = *(const bf16x8*)(wb + (w * 32 + l15) * 128 + kwb);
            bf16x8 b1v = *(const bf16x8*)(wb + (w * 32 + 16 + l15) * 128 + kwb);
            bf16x8 a0  = *(const bf16x8*)(sU + l15 * 1024 + kau);
            bf16x8 a1  = *(const bf16x8*)(sU + (16 + l15) * 1024 + kau);
            acc2[0][0] = MFMA(a0, b0,  acc2[0][0]);
            acc2[1][0] = MFMA(a1, b0,  acc2[1][0]);
            acc2[0][1] = MFMA(a0, b1v, acc2[0][1]);
            acc2[1][1] = MFMA(a1, b1v, acc2[1][1]);
        }
        asm volatile("s_waitcnt lgkmcnt(0)" ::: "memory");
        __builtin_amdgcn_s_barrier();
        __builtin_amdgcn_sched_barrier(0);
        if (c + 2 < 8) STAGE_W(cur, c + 2);
    }

    // ---- stage Wp (full 64KB into sWB); lands during LN ----
    #pragma unroll
    for (int i = 0; i < 8; ++i) {
        int id = i * 512 + tid;
        int col = id >> 5, slot = (id & 31) << 4;
        GLL16((const char*)WpT + (size_t)col * 512 + (slot ^ ((col & 7) << 4)),
              sWB + (size_t)(i * 512 + (tid & 448)) * 16);
    }

    // ---- x = e + f + b2 ; LN partials (identical to v5) ----
    float b2v[2], gv[2], btv[2];
    #pragma unroll
    for (int nj = 0; nj < 2; ++nj) {
        int col = w * 32 + nj * 16 + l15;
        b2v[nj] = b2[col]; gv[nj] = gamma[col]; btv[nj] = beta[col];
    }
    #pragma unroll
    for (int mi = 0; mi < 2; ++mi)
        #pragma unroll
        for (int r = 0; r < 4; ++r) {
            int row = mi * 16 + lk * 4 + r;
            int swr = (row & 7) << 4;
            float s1 = 0.f, s2 = 0.f;
            #pragma unroll
            for (int nj = 0; nj < 2; ++nj) {
                int col = w * 32 + nj * 16 + l15;
                float e = bf2f(*(const unsigned short*)(sE + row * 512 + ((col * 2) ^ swr)));
                float x = acc2[mi][nj][r] + b2v[nj] + e;
                acc2[mi][nj][r] = x;
                s1 += x; s2 = fmaf(x, x, s2);
            }
            s1 += __shfl_xor(s1, 1); s2 += __shfl_xor(s2, 1);
            s1 += __shfl_xor(s1, 2); s2 += __shfl_xor(s2, 2);
            s1 += __shfl_xor(s1, 4); s2 += __shfl_xor(s2, 4);
            s1 += __shfl_xor(s1, 8); s2 += __shfl_xor(s2, 8);
            if (l15 == 0) { sPart[row][w][0] = s1; sPart[row][w][1] = s2; }
        }
    __syncthreads();                       // drains Wp DMA too
    if (tid < 32) {
        float t1 = 0.f, t2 = 0.f;
        #pragma unroll
        for (int ww = 0; ww < 8; ++ww) { t1 += sPart[tid][ww][0]; t2 += sPart[tid][ww][1]; }
        float mu  = t1 * (1.f / 256.f);
        float var = t2 * (1.f / 256.f) - mu * mu;
        sMR[tid][0] = mu;
        sMR[tid][1] = rsqrtf(var + 1e-5f);
    }
    __syncthreads();
    // ---- h -> sE (bf16, swizzled; overwrites e) ----
    #pragma unroll
    for (int mi = 0; mi < 2; ++mi)
        #pragma unroll
        for (int r = 0; r < 4; ++r) {
            int row = mi * 16 + lk * 4 + r;
            int swr = (row & 7) << 4;
            float mu = sMR[row][0], rs = sMR[row][1];
            #pragma unroll
            for (int nj = 0; nj < 2; ++nj) {
                int col = w * 32 + nj * 16 + l15;
                float h = (acc2[mi][nj][r] - mu) * rs * gv[nj] + btv[nj];
                *(unsigned short*)(sE + row * 512 + ((col * 2) ^ swr)) = f2bf(h);
            }
        }
    __syncthreads();

    // ---- GEMM3: p = h @ Wp + bp; wave cols [w*16,+16), K=256, Wp in LDS ----
    f32x4 acc3[2];
    acc3[0] = acc3[1] = (f32x4){0.f, 0.f, 0.f, 0.f};
    #pragma unroll
    for (int ks = 0; ks < 8; ++ks) {
        int ka = (ks * 64 + lk * 16) ^ swl;
        bf16x8 b0 = *(const bf16x8*)(sWB + (w * 16 + l15) * 512 + ka);
        bf16x8 a0 = *(const bf16x8*)(sE + l15 * 512 + ka);
        bf16x8 a1 = *(const bf16x8*)(sE + (16 + l15) * 512 + ka);
        acc3[0] = MFMA(a0, b0, acc3[0]);
        acc3[1] = MFMA(a1, b0, acc3[1]);
    }
    {
        float bpv = bp[w * 16 + l15];
        #pragma unroll
        for (int mi = 0; mi < 2; ++mi)
            #pragma unroll
            for (int r = 0; r < 4; ++r) {
                int row = mi * 16 + lk * 4 + r;
                int col = w * 16 + l15;
                *(unsigned short*)(sU + row * 256 + col * 2) = f2bf(acc3[mi][r] + bpv);
            }
    }
    __syncthreads();
    {
        int row = tid >> 4, slot = (tid & 15) << 4;
        *(uint4*)((char*)ptab + (size_t)(n0 + row) * 256 + slot) =
            *(const uint4*)(sU + row * 256 + slot);
    }
}

// ---------------- sprep v5: 512 threads / chunk; Gram + W = (D+L)^-1 K ----
// Thread = (rr = tid&15, dq4 = tid>>4: 4 cols). Fully unrolled s-loop.
// Per-element fma order identical to v4 -> bit-identical output.
__global__ __launch_bounds__(512) void sprep_kernel(
    const int* __restrict__ seq, const unsigned short* __restrict__ ptab,
    char* __restrict__ SBg)
{
    __shared__ unsigned short sK[64 * 136];   // 17408 B, rows 272 B
    __shared__ float sG[10 * 16 * 17];        // 10880 B, block-major [q][r][c]
    __shared__ float sM[4 * 16 * 17];         //  4352 B
    __shared__ float sQ[64];                  //   256 B
    __shared__ float sW[64 * 132];            // 33792 B, rows 528 B

    const int blk  = blockIdx.x;              // 0..2047
    const int b    = blk >> 5, ch = blk & 31;
    const int t_hi = 2047 - (ch << 6);
    const int tid  = threadIdx.x;
    const int lane = tid & 63;
    const int wv   = tid >> 6;                // 0..7
    const int l15  = lane & 15, lk = lane >> 4;

    // ---- stage K rows: 1024 16B-chunks over 512 threads ----
    #pragma unroll
    for (int i = 0; i < 2; ++i) {
        int c = i * 512 + tid;
        int row = c >> 4, j = c & 15;
        int t = t_hi - row;
        if (t == 2047) {
            *(uint4*)((char*)sK + row * 272 + j * 16) = (uint4){0u, 0u, 0u, 0u};
        } else {
            int v = seq[b * 2048 + t];
            *(uint4*)((char*)sK + row * 272 + j * 16) =
                *(const uint4*)((const char*)(ptab + (size_t)v * 128) + j * 16);
        }
    }
    __syncthreads();

    // ---- Gram lower blocks via MFMA, 10 tiles over 8 waves ----
    {
        int q = 0;
        #pragma unroll
        for (int ti = 0; ti < 4; ++ti)
            #pragma unroll
            for (int tj = 0; tj <= ti; ++tj, ++q) {
                if ((q & 7) != wv) continue;           // wave-uniform branch
                f32x4 acc = (f32x4){0.f, 0.f, 0.f, 0.f};
                #pragma unroll
                for (int ks = 0; ks < 4; ++ks) {
                    bf16x8 fa = *(const bf16x8*)((const char*)sK + (ti * 16 + l15) * 272 + ks * 64 + lk * 16);
                    bf16x8 fb = *(const bf16x8*)((const char*)sK + (tj * 16 + l15) * 272 + ks * 64 + lk * 16);
                    acc = MFMA(fa, fb, acc);
                }
                #pragma unroll
                for (int r = 0; r < 4; ++r)
                    sG[q * 272 + (lk * 4 + r) * 17 + l15] = acc[r];
            }
    }
    __syncthreads();

    // ---- reciprocals of diagonal ----
    if (tid < 64) {
        int dq = (lk * (lk + 3)) >> 1;
        float d = sG[dq * 272 + l15 * 17 + l15] + 1e-6f;
        sQ[tid] = 1.0f / d;
    }
    __syncthreads();

    // ---- invert 4 diagonal blocks (tid<64: g = lk, column c = l15) ----
    if (tid < 64) {
        const int g = lk, c = l15;
        const float* Tg = &sG[((g * (g + 3)) >> 1) * 272];
        float qv[16], av[16], mcol[16];
        #pragma unroll
        for (int r = 0; r < 16; ++r) { qv[r] = sQ[g * 16 + r]; av[r] = 0.f; }
        #pragma unroll
        for (int r = 0; r < 16; ++r) {
            float mr = (((r == c) ? 1.f : 0.f) - av[r]) * qv[r];
            mcol[r] = mr;
            #pragma unroll
            for (int i = r + 1; i < 16; ++i)
                av[i] = fmaf(Tg[i * 17 + r], mr, av[i]);
        }
        #pragma unroll
        for (int r = 0; r < 16; ++r)
            sM[g * 272 + r * 17 + c] = mcol[r];
    }
    __syncthreads();

    // ---- W build: thread = (rr, dq4 covering cols [dq4*4, +4)) ----
    const int rr = tid & 15, dq4 = tid >> 4;
    #pragma unroll
    for (int s = 0; s < 4; ++s) {
        float a[4];
        {   // init from K row 16s+rr, cols [dq4*4, +4)
            uint2 kv = *(const uint2*)((const char*)sK + (16 * s + rr) * 272 + dq4 * 8);
            a[0] = bf2f((unsigned short)(kv.x & 0xffff));
            a[1] = bf2f((unsigned short)(kv.x >> 16));
            a[2] = bf2f((unsigned short)(kv.y & 0xffff));
            a[3] = bf2f((unsigned short)(kv.y >> 16));
        }
        #pragma unroll
        for (int j = 0; j < s; ++j) {           // compile-time bounds
            const float* Tb = &sG[(((s * (s + 1)) >> 1) + j) * 272];
            #pragma unroll
            for (int m = 0; m < 16; ++m) {
                float t = Tb[rr * 17 + m];
                f32x4 w0 = *(const f32x4*)&sW[(16 * j + m) * 132 + dq4 * 4];
                a[0] = fmaf(-t, w0.x, a[0]); a[1] = fmaf(-t, w0.y, a[1]);
                a[2] = fmaf(-t, w0.z, a[2]); a[3] = fmaf(-t, w0.w, a[3]);
            }
        }
        *(f32x4*)&sW[(16 * s + rr) * 132 + dq4 * 4] = (f32x4){a[0], a[1], a[2], a[3]};
        __syncthreads();
        float o[4] = {0.f, 0.f, 0.f, 0.f};
        #pragma unroll
        for (int cc = 0; cc < 16; ++cc) {       // W_s = M_s @ tmp
            float mm = sM[s * 272 + rr * 17 + cc];
            f32x4 w0 = *(const f32x4*)&sW[(16 * s + cc) * 132 + dq4 * 4];
            o[0] = fmaf(mm, w0.x, o[0]); o[1] = fmaf(mm, w0.y, o[1]);
            o[2] = fmaf(mm, w0.z, o[2]); o[3] = fmaf(mm, w0.w, o[3]);
        }
        __syncthreads();                        // all tmp reads done
        *(f32x4*)&sW[(16 * s + rr) * 132 + dq4 * 4] = (f32x4){o[0], o[1], o[2], o[3]};
        __syncthreads();
    }

    // ---- write WTP (transposed, packed bf16) + diag ----
    char* blob = SBg + (size_t)blk * 17408;
    unsigned* wtp = (unsigned*)blob;
    {
        int i = tid & 63;
        #pragma unroll
        for (int dg = 0; dg < 8; ++dg) {
            int d2 = (tid >> 6) * 8 + dg;
            float2 wvp = *(const float2*)&sW[i * 132 + d2 * 2];
            wtp[d2 * 64 + i] = (unsigned)f2bf(wvp.x) | ((unsigned)f2bf(wvp.y) << 16);
        }
    }
    if (tid < 64) {
        int dq = (lk * (lk + 3)) >> 1;
        float d = sG[dq * 272 + l15 * 17 + l15] + 1e-6f;
        *(float*)(blob + 16384 + tid * 4) = d;
    }
}

// ---------------- serial chunked scan v2: 8-wave cooperative chunk body ----
__global__ __launch_bounds__(512) void scan_kernel(
    const int* __restrict__ seq, const unsigned short* __restrict__ ptab,
    const char* __restrict__ SBg, const float* __restrict__ zrow,
    float* __restrict__ csb)
{
    __shared__ int sSeq[2048];
    __shared__ unsigned short sKb[2][8192];      // [64][128] bf16, linear
    __shared__ __align__(16) char sBlob[2][16640]; // WTP 16K + diag 256B
    __shared__ float  sPZ[8][64];                // per-wave z partials
    __shared__ float2 sPC[8][64];                // per-wave du partials / csv

    const int b    = blockIdx.x;
    const int tid  = threadIdx.x;
    const int lane = tid & 63;
    const int w    = tid >> 6;

    *(int4*)&sSeq[tid * 4] = *(const int4*)&seq[b * 2048 + tid * 4];
    float u0, u1;                                // u pair (2*lane, 2*lane+1)
    {
        int vq = seq[b * 2048 + 2047];
        unsigned pk = *(const unsigned*)(ptab + (size_t)vq * 128 + lane * 2);
        u0 = bf2f((unsigned short)(pk & 0xffff));
        u1 = bf2f((unsigned short)(pk >> 16));
    }
    float csv0 = 0.f, csv1 = 0.f;
    __syncthreads();            // once: sSeq visible (drains vmcnt, harmless here)

    auto STAGE = [&](int s, int ch) {            // 4 GLLs/wave (wave 7: 5)
        int t_hi = 2047 - (ch << 6);
        #pragma unroll
        for (int kk = 0; kk < 2; ++kk) {
            int k = w * 2 + kk;
            int g = k * 64 + lane;
            int r = g >> 4, sd = g & 15;
            int t = t_hi - r;
            int v = sSeq[t];
            const char* srow = (t == 2047) ? (const char*)zrow
                                           : (const char*)(ptab + (size_t)v * 128);
            GLL16(srow + sd * 16, (char*)sKb[s] + k * 1024);
        }
        const char* bsrc = SBg + ((size_t)b * 32 + ch) * 17408;
        #pragma unroll
        for (int kk = 0; kk < 2; ++kk) {
            int k = w * 2 + kk;
            GLL16(bsrc + k * 1024 + lane * 16, (char*)sBlob[s] + k * 1024);
        }
        if (w == 7)
            GLL4(bsrc + 16384 + lane * 4, (char*)sBlob[s] + 16384);
    };

    STAGE(0, 0); STAGE(1, 1);

    #pragma unroll 1
    for (int c = 0; c < 32; ++c) {
        const int cur = c & 1;
        if (c < 31) {
            if (w == 7) asm volatile("s_waitcnt vmcnt(5)" ::: "memory");
            else        asm volatile("s_waitcnt vmcnt(4)" ::: "memory");
        } else {
            asm volatile("s_waitcnt vmcnt(0)" ::: "memory");
        }
        __builtin_amdgcn_s_barrier();            // B0: all waves' DMA landed
        __builtin_amdgcn_sched_barrier(0);

        const unsigned short* kb = sKb[cur];
        const unsigned* wt = (const unsigned*)(sBlob[cur]);
        const float* dgv = (const float*)(sBlob[cur] + 16384);

        // phase Z partial: wave w covers d2 in [8w, 8w+8); lane = i
        float zp = 0.f;
        #pragma unroll
        for (int j = 0; j < 8; ++j) {
            int d2 = w * 8 + j;
            unsigned wp = wt[d2 * 64 + lane];    // conflict-free
            float ua = __shfl(u0, d2);
            float ub = __shfl(u1, d2);
            zp = fmaf(bf2f((unsigned short)(wp & 0xffff)), ua, zp);
            zp = fmaf(bf2f((unsigned short)(wp >> 16)),    ub, zp);
        }
        sPZ[w][lane] = zp;
        asm volatile("s_waitcnt lgkmcnt(0)" ::: "memory");
        __builtin_amdgcn_s_barrier();            // B1
        __builtin_amdgcn_sched_barrier(0);

        // redundant full reduce (identical order in every wave) -> z, ci
        float z = 0.f;
        #pragma unroll
        for (int ww = 0; ww < 8; ++ww) z += sPZ[ww][lane];
        float ci = z * dgv[lane];

        // phase C partial: wave w covers i in [8w, 8w+8); lane = d-pair
        float du0 = 0.f, du1 = 0.f;
        #pragma unroll
        for (int j = 0; j < 8; ++j) {
            int i = w * 8 + j;
            float zi  = __shfl(z, i);
            float cii = __shfl(ci, i);
            unsigned kp = *(const unsigned*)((const char*)kb + i * 256 + lane * 4);
            float k0 = bf2f((unsigned short)(kp & 0xffff));
            float k1 = bf2f((unsigned short)(kp >> 16));
            du0  = fmaf(zi,  k0, du0);  du1  = fmaf(zi,  k1, du1);
            csv0 = fmaf(cii, k0, csv0); csv1 = fmaf(cii, k1, csv1);
        }
        sPC[w][lane] = make_float2(du0, du1);
        asm volatile("s_waitcnt lgkmcnt(0)" ::: "memory");
        __builtin_amdgcn_s_barrier();            // B2: buf cur fully consumed
        __builtin_amdgcn_sched_barrier(0);

        if (c + 2 < 32) STAGE(cur, c + 2);       // overwrite is now safe

        float s0 = 0.f, s1 = 0.f;
        #pragma unroll
        for (int ww = 0; ww < 8; ++ww) {
            float2 p = sPC[ww][lane];
            s0 += p.x; s1 += p.y;
        }
        u0 -= s0; u1 -= s1;
    }

    // final csv reduce across waves
    asm volatile("s_waitcnt lgkmcnt(0)" ::: "memory");
    __builtin_amdgcn_s_barrier();                // all u-update reads done
    sPC[w][lane] = make_float2(csv0, csv1);
    asm volatile("s_waitcnt lgkmcnt(0)" ::: "memory");
    __builtin_amdgcn_s_barrier();
    if (w == 0) {
        float a0 = 0.f, a1 = 0.f;
        #pragma unroll
        for (int ww = 0; ww < 8; ++ww) {
            float2 p = sPC[ww][lane];
            a0 += p.x; a1 += p.y;
        }
        csb[b * 128 + lane * 2]     = a0;
        csb[b * 128 + lane * 2 + 1] = a1;
    }
}

// ---------------- out v2: 500 blocks; block = 64 cols x 4 row-groups ------
__global__ __launch_bounds__(256) void out_kernel(
    const float* __restrict__ cs, const float* __restrict__ Wo,
    const float* __restrict__ bo, float* __restrict__ out)
{
    __shared__ float sC[64 * 128];
    const int tid = threadIdx.x;
    #pragma unroll
    for (int r = 0; r < 8; ++r)
        ((float4*)sC)[r * 256 + tid] = ((const float4*)cs)[r * 256 + tid];
    __syncthreads();

    const int j  = blockIdx.x * 64 + (tid & 63);   // vocab col
    const int rg = tid >> 6;                       // 0..3 -> rows rg*16..+16
    float acc[16];
    #pragma unroll
    for (int r = 0; r < 16; ++r) acc[r] = 0.f;
    for (int k0 = 0; k0 < 128; k0 += 4) {
        float w0 = Wo[(size_t)(k0 + 0) * Vv + j];
        float w1 = Wo[(size_t)(k0 + 1) * Vv + j];
        float w2 = Wo[(size_t)(k0 + 2) * Vv + j];
        float w3 = Wo[(size_t)(k0 + 3) * Vv + j];
        #pragma unroll
        for (int r = 0; r < 16; ++r) {
            float4 c = *(const float4*)&sC[(rg * 16 + r) * 128 + k0];
            acc[r] = fmaf(c.x, w0, fmaf(c.y, w1, fmaf(c.z, w2, fmaf(c.w, w3, acc[r]))));
        }
    }
    float bj = bo[j];
    #pragma unroll
    for (int r = 0; r < 16; ++r)
        out[(size_t)(rg * 16 + r) * Vv + j] = acc[r] + bj;
}

extern "C" void kernel_launch(void* const* d_in, const int* in_sizes, int n_in,
                              void* d_out, int out_size, void* d_ws, size_t ws_size,
                              hipStream_t stream)
{
    const int*   seq   = (const int*)  d_in[0];
    const float* embed = (const float*)d_in[1];
    const float* W1    = (const float*)d_in[2];
    const float* b1    = (const float*)d_in[3];
    const float* W2    = (const float*)d_in[4];
    const float* b2    = (const float*)d_in[5];
    const float* gamma = (const float*)d_in[6];
    const float* beta  = (const float*)d_in[7];
    const float* Wp    = (const float*)d_in[8];
    const float* bp    = (const float*)d_in[9];
    const float* Wo    = (const float*)d_in[10];
    const float* bo    = (const float*)d_in[11];
    float* out = (float*)d_out;

    // ws layout: ptab | BIG (SBg  OVERLAPS  embbf+U; serial stream makes it safe:
    // embbf/U are dead before sprep writes SBg) | weight tables | csb | zrow
    char* wsb = (char*)d_ws;
    unsigned short* ptab  = (unsigned short*)(wsb);                //  8,192,000 B
    char*           SBg   = wsb + 8192000;                         // 35,651,584 B (region 49,152,000)
    unsigned short* embbf = (unsigned short*)(wsb + 8192000);      // 16,384,000 B (aliases SBg)
    unsigned short* Ug    = (unsigned short*)(wsb + 24576000);     // 32,768,000 B (aliases SBg)
    unsigned short* W1T   = (unsigned short*)(wsb + 57344000);     //    262,144 B
    unsigned short* W2T   = (unsigned short*)(wsb + 57606144);     //    262,144 B
    unsigned short* WpT   = (unsigned short*)(wsb + 57868288);     //     65,536 B
    float*          csb   = (float*)(wsb + 57933824);              //     32,768 B
    float*          zrow  = (float*)(wsb + 57966592);              //        256 B

    prep_kernel<<<576, 256, 0, stream>>>(W1, W2, Wp, W1T, W2T, WpT, zrow);
    embconv_kernel<<<4000, 256, 0, stream>>>(embed, embbf);
    encA_kernel<<<1000, 512, 0, stream>>>(embbf, W1T, b1, Ug);
    encB_kernel<<<1000, 512, 0, stream>>>(embbf, Ug, (const char*)W2T, b2,
                                          gamma, beta, WpT, bp, ptab);
    sprep_kernel<<<2048, 512, 0, stream>>>(seq, ptab, SBg);
    scan_kernel<<<64, 512, 0, stream>>>(seq, ptab, SBg, zrow, csb);
    out_kernel<<<Vv / 64, 256, 0, stream>>>(csb, Wo, bo, out);
}